// Round 4
// baseline (959.492 us; speedup 1.0000x reference)
//
#include <hip/hip_runtime.h>
#include <stdint.h>

#define DIM 1536
#define SLEN 3900
#define SPAD 3904   // padded V^T row stride (16B-aligned rows)
#define NH 12
#define HD 128

typedef __bf16 bf16x8 __attribute__((ext_vector_type(8)));
typedef float f32x4 __attribute__((ext_vector_type(4)));

__device__ __forceinline__ float b2f(uint16_t u) {
  union { uint32_t i; float f; } x; x.i = ((uint32_t)u) << 16; return x.f;
}
__device__ __forceinline__ uint16_t f2b(float f) {
  union { float f; uint32_t i; } x; x.f = f;
  uint32_t r = (x.i + 0x7fffu + ((x.i >> 16) & 1u)) >> 16;
  return (uint16_t)r;
}
__device__ __forceinline__ bf16x8 ld8bf(const uint16_t* p) {
  bf16x8 r; __builtin_memcpy(&r, p, 16); return r;
}
__device__ __forceinline__ void st8(uint16_t* p, bf16x8 v) {
  __builtin_memcpy(p, &v, 16);
}
// dtype-adaptive 8-element load (eoff = element offset, multiple of 8)
__device__ __forceinline__ bf16x8 ld8any(const void* base, size_t eoff, int f32) {
  if (f32) {
    const float* s = (const float*)base + eoff;
    uint16_t t[8];
#pragma unroll
    for (int i = 0; i < 8; i++) t[i] = f2b(s[i]);
    bf16x8 r; __builtin_memcpy(&r, t, 16); return r;
  }
  return ld8bf((const uint16_t*)base + eoff);
}

// ---------------------------------------------------- dtype detection (device)
// fp32 N(0,1) data read as float: finite, |v|<1000. bf16 data read as float:
// exponent comes from a mantissa halfword -> |v|~1e38 or inf. Unambiguous.
__global__ void detect(const void* x, int* flag) {
  if (threadIdx.x == 0 && blockIdx.x == 0) {
    const uint32_t* xu = (const uint32_t*)x;
    int cnt = 0;
    for (int i = 0; i < 256; i++) {
      uint32_t u = xu[i];
      uint32_t ex = (u >> 23) & 0xFF;
      union { uint32_t i; float f; } c; c.i = u;
      float av = c.f < 0.f ? -c.f : c.f;
      if (ex != 0xFF && av < 1000.f) cnt++;
    }
    *flag = (cnt >= 240) ? 1 : 0;
  }
}

// -------------------------------- canonicalize small arrays (freqs + 6 vecs)
__global__ __launch_bounds__(256) void conv_arr(
    const void* s0, const void* s1, const void* s2, const void* s3,
    const void* s4, const void* s5, const void* s6,
    uint16_t* dst, const int* flag) {
  const void* srcs[7] = {s0, s1, s2, s3, s4, s5, s6};
  const int ns[7]   = {131072, 1536, 1536, 1536, 1536, 1536, 1536};
  const int offs[7] = {0, 131072, 132608, 134144, 135680, 137216, 138752};
  const int a = blockIdx.y;
  const int i = blockIdx.x * 256 + threadIdx.x;
  const int f = *flag;
  if (i < ns[a]) {
    uint16_t v = f ? f2b(((const float*)srcs[a])[i]) : ((const uint16_t*)srcs[a])[i];
    dst[offs[a] + i] = v;
  }
}

// ------------------------------------------------- transpose W (dtype-adaptive)
__global__ __launch_bounds__(256) void transposeW2(
    const void* src, uint16_t* dst, const int* flag) {
  __shared__ uint16_t t[32][33];
  const int f = *flag;
  const int bx = blockIdx.x * 32, by = blockIdx.y * 32;
  const int tx = threadIdx.x & 31, ty = threadIdx.x >> 5;  // ty 0..7
#pragma unroll
  for (int i = 0; i < 32; i += 8) {
    size_t idx = (size_t)(by + ty + i) * DIM + bx + tx;
    t[ty + i][tx] = f ? f2b(((const float*)src)[idx]) : ((const uint16_t*)src)[idx];
  }
  __syncthreads();
#pragma unroll
  for (int i = 0; i < 32; i += 8)
    dst[(size_t)(bx + ty + i) * DIM + by + tx] = t[tx][ty + i];
}

// ------------------------------------------------- GEMM: C = A * BT^T (+bias)
// A [M][DIM] (bf16 or fp32 per flag); BT [DIM][DIM] bf16 canonical.
// mode 0: C [M][DIM] (+bias, dtype per o_may_f32&&flag). mode 1: head-split
// C [12][SLEN][128] bf16. 128x128 tile, BK=32, 4 waves (2x2), 4x4 16x16x32.
__global__ __launch_bounds__(256) void gemm2(
    const void* A, const uint16_t* BT, void* C, const uint16_t* bias,
    int M, int mode, int a_may_f32, int o_may_f32, const int* flag) {
  __shared__ __align__(16) uint16_t sA[128 * 32];
  __shared__ __align__(16) uint16_t sB[128 * 32];
  const int af32 = a_may_f32 && *flag;
  const int of32 = o_may_f32 && *flag;
  const int m0 = blockIdx.x * 128;
  const int n0 = blockIdx.y * 128;
  const int tid = threadIdx.x;
  const int wave = tid >> 6, lane = tid & 63;
  const int mh = (wave >> 1) * 64, nh = (wave & 1) * 64;
  const int fm = mh + (lane & 15);
  const int fn = nh + (lane & 15);
  const int ko = (lane >> 4) * 8;

  f32x4 acc[4][4];
  const f32x4 z4 = {0.f, 0.f, 0.f, 0.f};
#pragma unroll
  for (int i = 0; i < 4; i++)
#pragma unroll
    for (int j = 0; j < 4; j++) acc[i][j] = z4;

  for (int k0 = 0; k0 < DIM; k0 += 32) {
    __syncthreads();  // protect previous iteration's LDS reads
#pragma unroll
    for (int j = 0; j < 2; j++) {
      int idx = tid + j * 256;      // 0..511
      int row = idx >> 2;           // 0..127
      int cc = (idx & 3) * 8;       // 0,8,16,24
      int ra = m0 + row; ra = ra < M ? ra : M - 1;
      st8(sA + row * 32 + cc, ld8any(A, (size_t)ra * DIM + k0 + cc, af32));
      int rb = n0 + row;            // N=1536 exact multiple of 128
      st8(sB + row * 32 + cc, ld8bf(BT + (size_t)rb * DIM + k0 + cc));
    }
    __syncthreads();
    bf16x8 fa[4], fb[4];
#pragma unroll
    for (int i = 0; i < 4; i++) {
      fa[i] = ld8bf(sA + (fm + i * 16) * 32 + ko);
      fb[i] = ld8bf(sB + (fn + i * 16) * 32 + ko);
    }
#pragma unroll
    for (int i = 0; i < 4; i++)
#pragma unroll
      for (int j = 0; j < 4; j++)
        acc[i][j] = __builtin_amdgcn_mfma_f32_16x16x32_bf16(fa[i], fb[j], acc[i][j], 0, 0, 0);
  }
  // epilogue: D row=(lane>>4)*4+r, col=lane&15 (verified m89/m91)
#pragma unroll
  for (int j = 0; j < 4; j++) {
    int col = n0 + nh + j * 16 + (lane & 15);
    float bvv = (mode == 0 && bias) ? b2f(bias[col]) : 0.f;
#pragma unroll
    for (int i = 0; i < 4; i++) {
      int row = m0 + mh + i * 16 + (lane >> 4) * 4;
#pragma unroll
      for (int r = 0; r < 4; r++) {
        if (row + r < M) {
          float val = acc[i][j][r] + bvv;
          if (mode == 0) {
            if (of32) ((float*)C)[(size_t)(row + r) * DIM + col] = val;
            else ((uint16_t*)C)[(size_t)(row + r) * DIM + col] = f2b(val);
          } else {
            ((uint16_t*)C)[(size_t)(col >> 7) * ((size_t)SLEN * HD) +
                           (size_t)(row + r) * HD + (col & 127)] = f2b(val);
          }
        }
      }
    }
  }
}

// --------------------------------------- RMSNorm + gamma + 3D RoPE for Q / K
// In/out (in-place): Qb/Kb head-split [12][SLEN][128] bf16 (pre-bias).
__global__ __launch_bounds__(256) void norm_rope(
    uint16_t* __restrict__ Qb, uint16_t* __restrict__ Kb,
    const uint16_t* __restrict__ bq, const uint16_t* __restrict__ bk,
    const uint16_t* __restrict__ gq, const uint16_t* __restrict__ gk,
    const uint16_t* __restrict__ freqs, const int* __restrict__ gsz) {
  const int s = blockIdx.x;
  const int isK = blockIdx.y;
  uint32_t* B = (uint32_t*)(isK ? Kb : Qb);
  const uint32_t* br = (const uint32_t*)(isK ? bk : bq);
  const uint32_t* gr = (const uint32_t*)(isK ? gk : gq);
  const int tid = threadIdx.x;
  float va[3], vb[3];
  float ss = 0.f;
#pragma unroll
  for (int i = 0; i < 3; i++) {
    int p = tid + i * 256;  // pair index 0..767 within the logical 1536-row
    int h = p >> 6, j = p & 63;
    size_t a = (size_t)h * (SLEN * 64) + (size_t)s * 64 + j;
    uint32_t u = B[a], ub = br[p];
    float x0 = b2f((uint16_t)(u & 0xffff)) + b2f((uint16_t)(ub & 0xffff));
    float x1 = b2f((uint16_t)(u >> 16)) + b2f((uint16_t)(ub >> 16));
    va[i] = x0; vb[i] = x1; ss += x0 * x0 + x1 * x1;
  }
#pragma unroll
  for (int o = 32; o > 0; o >>= 1) ss += __shfl_down(ss, o, 64);
  __shared__ float red[4];
  if ((tid & 63) == 0) red[tid >> 6] = ss;
  __syncthreads();
  ss = red[0] + red[1] + red[2] + red[3];
  const float rr = rsqrtf(ss * (1.0f / DIM) + 1e-6f);
  const int H = gsz[1], W = gsz[2];
  const int hw = H * W;
  const int fi = s / hw, rem = s - fi * hw;
  const int hi = rem / W, wi = rem - hi * W;
#pragma unroll
  for (int i = 0; i < 3; i++) {
    int p = tid + i * 256;
    int h = p >> 6, j = p & 63;
    int prow = (j < 22) ? fi : (j < 43) ? hi : wi;  // c0=22, c3=21
    uint32_t fu = ((const uint32_t*)freqs)[prow * 64 + j];
    float cs = b2f((uint16_t)(fu & 0xffff)), sn = b2f((uint16_t)(fu >> 16));
    uint32_t gu = gr[p];
    float na = va[i] * rr * b2f((uint16_t)(gu & 0xffff));
    float nb = vb[i] * rr * b2f((uint16_t)(gu >> 16));
    float ra = na * cs - nb * sn;
    float rb = na * sn + nb * cs;
    size_t a = (size_t)h * (SLEN * 64) + (size_t)s * 64 + j;
    B[a] = (uint32_t)f2b(ra) | ((uint32_t)f2b(rb) << 16);
  }
}

// ----------------- V: bias + reformat [12][SLEN][128] -> V^T [12][128][SPAD]
__global__ __launch_bounds__(256) void v_reformat(
    const uint16_t* __restrict__ Vb, const uint16_t* __restrict__ bv,
    uint16_t* __restrict__ VT) {
  __shared__ uint16_t t[128][136];
  const int head = blockIdx.x;
  const int s0 = blockIdx.y * 128;
  const int tid = threadIdx.x;
  const int cb = (tid & 15) * 8, rb = tid >> 4;
  const uint16_t* Vh = Vb + (size_t)head * SLEN * HD;
  float bvf[8];
#pragma unroll
  for (int q = 0; q < 8; q++) bvf[q] = b2f(bv[head * HD + cb + q]);
#pragma unroll
  for (int pass = 0; pass < 8; pass++) {
    int r = rb + pass * 16;
    int s = s0 + r; int sc = s < SLEN ? s : SLEN - 1;
    uint16_t u[8];
    __builtin_memcpy(u, Vh + (size_t)sc * HD + cb, 16);
#pragma unroll
    for (int q = 0; q < 8; q++) t[r][cb + q] = f2b(b2f(u[q]) + bvf[q]);
  }
  __syncthreads();
  const int sb = (tid & 15) * 8, db = tid >> 4;
#pragma unroll
  for (int pass = 0; pass < 8; pass++) {
    int d = db + pass * 16;
    uint16_t out[8] __attribute__((aligned(16)));
#pragma unroll
    for (int i2 = 0; i2 < 8; i2++) {
      int s = s0 + sb + i2;
      out[i2] = (s < SLEN) ? t[sb + i2][d] : (uint16_t)0;  // zero-fill pad cols
    }
    size_t base = ((size_t)head * HD + d) * SPAD + s0 + sb;
    if (s0 + sb + 8 <= SLEN) {
      __builtin_memcpy(VT + base, out, 16);
    } else {
#pragma unroll
      for (int i2 = 0; i2 < 8; i2++) {
        int s = s0 + sb + i2;
        if (s < SPAD) VT[base + i2] = out[i2];
      }
    }
  }
}

// ------------------------------------------------ flash attention (bf16 MFMA)
// grid (12 heads, 61 q-tiles); 4 waves; wave owns 16 q rows, full d=128.
__global__ __launch_bounds__(256) void attn(
    const uint16_t* __restrict__ Q, const uint16_t* __restrict__ K,
    const uint16_t* __restrict__ VT, uint16_t* __restrict__ O,
    const int* __restrict__ seq_lens) {
  __shared__ __align__(16) uint16_t sQ[64 * 128];  // [q][d]
  __shared__ __align__(16) uint16_t sK[64 * 128];  // [kk][d]
  __shared__ __align__(16) uint16_t sV[128 * 64];  // [d][kk]  (from V^T)
  __shared__ __align__(16) uint16_t sP[64 * 64];   // [q][kk]
  const int head = blockIdx.x;
  const int q0 = blockIdx.y * 64;
  const int tid = threadIdx.x;
  const int wave = tid >> 6, lane = tid & 63;
  int sl = seq_lens[0];
  const int seqlen = sl < SLEN ? sl : SLEN;
  const uint16_t* Qh = Q + (size_t)head * SLEN * HD;
  const uint16_t* Kh = K + (size_t)head * SLEN * HD;
  const uint16_t* Vh = VT + (size_t)head * HD * SPAD;

  // stage Q tile once: 64 rows x 128 cols
#pragma unroll
  for (int ps = 0; ps < 4; ps++) {
    int idx = tid + ps * 256;
    int row = idx >> 4, cc = (idx & 15) * 8;
    int qg = q0 + row; qg = qg < SLEN ? qg : SLEN - 1;
    st8(sQ + row * 128 + cc, ld8bf(Qh + (size_t)qg * HD + cc));
  }
  __syncthreads();

  f32x4 o[8];
  const f32x4 z4 = {0.f, 0.f, 0.f, 0.f};
#pragma unroll
  for (int j = 0; j < 8; j++) o[j] = z4;
  float m_r[4] = {-3.0e38f, -3.0e38f, -3.0e38f, -3.0e38f};
  float l_r[4] = {0.f, 0.f, 0.f, 0.f};

  const int fm = lane & 15;
  const int ko = (lane >> 4) * 8;
  const float scale = 0.08838834764831845f;  // 1/sqrt(128)
  const float LOG2E = 1.4426950408889634f;

  for (int kv0 = 0; kv0 < SLEN; kv0 += 64) {
    __syncthreads();
    // stage K: 64 rows x 128 cols
#pragma unroll
    for (int ps = 0; ps < 4; ps++) {
      int idx = tid + ps * 256;
      int row = idx >> 4, cc = (idx & 15) * 8;
      int kg = kv0 + row; kg = kg < SLEN ? kg : SLEN - 1;
      st8(sK + row * 128 + cc, ld8bf(Kh + (size_t)kg * HD + cc));
    }
    // stage V^T: 128 rows(d) x 64 cols(kv)
#pragma unroll
    for (int ps = 0; ps < 4; ps++) {
      int idx = tid + ps * 256;
      int d = idx >> 3, cc = (idx & 7) * 8;
      st8(sV + d * 64 + cc, ld8bf(Vh + (size_t)d * SPAD + kv0 + cc));
    }
    __syncthreads();

    // QK^T : 16 mfma
    f32x4 sc[4];
#pragma unroll
    for (int kk = 0; kk < 4; kk++) sc[kk] = z4;
#pragma unroll
    for (int kc = 0; kc < 4; kc++) {
      bf16x8 aq = ld8bf(sQ + (wave * 16 + fm) * 128 + kc * 32 + ko);
#pragma unroll
      for (int kk = 0; kk < 4; kk++) {
        bf16x8 bkf = ld8bf(sK + (kk * 16 + fm) * 128 + kc * 32 + ko);
        sc[kk] = __builtin_amdgcn_mfma_f32_16x16x32_bf16(aq, bkf, sc[kk], 0, 0, 0);
      }
    }
    // scale + key mask
#pragma unroll
    for (int kk = 0; kk < 4; kk++) {
      int col = kv0 + kk * 16 + fm;
      bool valid = col < seqlen;
#pragma unroll
      for (int r = 0; r < 4; r++)
        sc[kk][r] = valid ? sc[kk][r] * scale : -3.0e38f;
    }
    // online softmax (rows live in 16-lane groups; butterfly over lane&15)
    float pv[4][4];
#pragma unroll
    for (int r = 0; r < 4; r++) {
      float v = fmaxf(fmaxf(sc[0][r], sc[1][r]), fmaxf(sc[2][r], sc[3][r]));
#pragma unroll
      for (int off = 1; off < 16; off <<= 1) v = fmaxf(v, __shfl_xor(v, off, 64));
      float mnew = fmaxf(m_r[r], v);
      float al = exp2f((m_r[r] - mnew) * LOG2E);
      float sum = 0.f;
#pragma unroll
      for (int kk = 0; kk < 4; kk++) {
        float p = exp2f((sc[kk][r] - mnew) * LOG2E);
        pv[kk][r] = p; sum += p;
      }
#pragma unroll
      for (int off = 1; off < 16; off <<= 1) sum += __shfl_xor(sum, off, 64);
      l_r[r] = l_r[r] * al + sum;
      m_r[r] = mnew;
#pragma unroll
      for (int j = 0; j < 8; j++) o[j][r] *= al;
    }
    // P: C-layout -> A-layout via LDS round trip (m120 pattern)
#pragma unroll
    for (int kk = 0; kk < 4; kk++)
#pragma unroll
      for (int r = 0; r < 4; r++)
        sP[(wave * 16 + (lane >> 4) * 4 + r) * 64 + kk * 16 + fm] = f2b(pv[kk][r]);
    __syncthreads();
    // PV : 16 mfma
#pragma unroll
    for (int kc = 0; kc < 2; kc++) {
      bf16x8 ap = ld8bf(sP + (wave * 16 + fm) * 64 + kc * 32 + ko);
#pragma unroll
      for (int j = 0; j < 8; j++) {
        bf16x8 bvf = ld8bf(sV + (j * 16 + fm) * 64 + kc * 32 + ko);
        o[j] = __builtin_amdgcn_mfma_f32_16x16x32_bf16(ap, bvf, o[j], 0, 0, 0);
      }
    }
  }
  // epilogue: normalize and write [s][head*128+d]
#pragma unroll
  for (int r = 0; r < 4; r++) {
    int row = q0 + wave * 16 + (lane >> 4) * 4 + r;
    if (row < SLEN) {
      float inv = 1.0f / l_r[r];
#pragma unroll
      for (int j = 0; j < 8; j++) {
        int col = head * HD + j * 16 + fm;
        O[(size_t)row * DIM + col] = f2b(o[j][r] * inv);
      }
    }
  }
}

// ----------------------------------------------------------------- launcher
extern "C" void kernel_launch(void* const* d_in, const int* in_sizes, int n_in,
                              void* d_out, int out_size, void* d_ws, size_t ws_size,
                              hipStream_t stream) {
  const void* x     = d_in[0];
  const int* seq_lens = (const int*)d_in[1];
  const int* gsz      = (const int*)d_in[2];
  const void* freqs = d_in[3];
  const void* Wq    = d_in[4];
  const void* bq    = d_in[5];
  const void* Wk    = d_in[6];
  const void* bk    = d_in[7];
  const void* Wv    = d_in[8];
  const void* bv    = d_in[9];
  const void* Wo    = d_in[10];
  const void* bo    = d_in[11];
  const void* gq    = d_in[12];
  const void* gk    = d_in[13];

  // workspace layout (~53 MB)
  char* p = (char*)d_ws;
  int* flag = (int*)p;          p += 256;
  uint16_t* vec = (uint16_t*)p; p += 140288 * 2 + 256;             // 0.28 MB
  uint16_t* WT  = (uint16_t*)p; p += (size_t)DIM * DIM * 2;        // 4.72 MB
  uint16_t* Qb  = (uint16_t*)p; p += (size_t)NH * SLEN * HD * 2;   // 11.98 MB
  uint16_t* Kb  = (uint16_t*)p; p += (size_t)NH * SLEN * HD * 2;   // 11.98 MB
  uint16_t* Vb  = (uint16_t*)p; p += (size_t)NH * SLEN * HD * 2;   // 11.98 MB
  uint16_t* VTb = (uint16_t*)p; p += (size_t)NH * HD * SPAD * 2;   // 11.99 MB
  uint16_t* AO  = Vb;  // attn reads VTb/Qb/Kb only; Vb free by then

  uint16_t* freqsC = vec;
  uint16_t* bqC = vec + 131072;
  uint16_t* bkC = bqC + 1536;
  uint16_t* bvC = bkC + 1536;
  uint16_t* boC = bvC + 1536;
  uint16_t* gqC = boC + 1536;
  uint16_t* gkC = gqC + 1536;

  detect<<<1, 64, 0, stream>>>(x, flag);
  conv_arr<<<dim3(512, 7), 256, 0, stream>>>(freqs, bq, bk, bv, bo, gq, gk, vec, flag);

  transposeW2<<<dim3(48, 48), 256, 0, stream>>>(Wq, WT, flag);
  gemm2<<<dim3(31, 12), 256, 0, stream>>>(x, WT, Qb, nullptr, SLEN, 1, 1, 0, flag);
  transposeW2<<<dim3(48, 48), 256, 0, stream>>>(Wk, WT, flag);
  gemm2<<<dim3(31, 12), 256, 0, stream>>>(x, WT, Kb, nullptr, SLEN, 1, 1, 0, flag);
  transposeW2<<<dim3(48, 48), 256, 0, stream>>>(Wv, WT, flag);
  gemm2<<<dim3(31, 12), 256, 0, stream>>>(x, WT, Vb, nullptr, SLEN, 1, 1, 0, flag);

  norm_rope<<<dim3(SLEN, 2), 256, 0, stream>>>(Qb, Kb, bqC, bkC, gqC, gkC, freqsC, gsz);
  v_reformat<<<dim3(NH, 31), 256, 0, stream>>>(Vb, bvC, VTb);
  attn<<<dim3(NH, 61), 256, 0, stream>>>(Qb, Kb, VTb, AO, seq_lens);

  transposeW2<<<dim3(48, 48), 256, 0, stream>>>(Wo, WT, flag);
  gemm2<<<dim3(31, 12), 256, 0, stream>>>(AO, WT, d_out, boC, SLEN, 0, 0, 1, flag);
}

// Round 7
// 792.008 us; speedup vs baseline: 1.2115x; 1.2115x over previous
//
#include <hip/hip_runtime.h>
#include <stdint.h>

#define DIM 1536
#define SLEN 3900
#define SPAD 3904   // padded V^T row stride (16B-aligned rows)
#define NH 12
#define HD 128
#define SKP 136     // sQ/sK row stride (elems): 272B pitch breaks 128B bank period
#define SVP 72      // sV/sP row stride (elems): 144B pitch

typedef __bf16 bf16x8 __attribute__((ext_vector_type(8)));
typedef float f32x4 __attribute__((ext_vector_type(4)));

__device__ __forceinline__ float b2f(uint16_t u) {
  union { uint32_t i; float f; } x; x.i = ((uint32_t)u) << 16; return x.f;
}
__device__ __forceinline__ uint16_t f2b(float f) {
  union { float f; uint32_t i; } x; x.f = f;
  uint32_t r = (x.i + 0x7fffu + ((x.i >> 16) & 1u)) >> 16;
  return (uint16_t)r;
}
__device__ __forceinline__ bf16x8 ld8bf(const uint16_t* p) {
  bf16x8 r; __builtin_memcpy(&r, p, 16); return r;
}
__device__ __forceinline__ void st8(uint16_t* p, bf16x8 v) {
  __builtin_memcpy(p, &v, 16);
}
// dtype-adaptive 8-element load (eoff = element offset, multiple of 8)
__device__ __forceinline__ bf16x8 ld8any(const void* base, size_t eoff, int f32) {
  if (f32) {
    const float* s = (const float*)base + eoff;
    uint16_t t[8];
#pragma unroll
    for (int i = 0; i < 8; i++) t[i] = f2b(s[i]);
    bf16x8 r; __builtin_memcpy(&r, t, 16); return r;
  }
  return ld8bf((const uint16_t*)base + eoff);
}

// ---------------------------------------------------- dtype detection (device)
__global__ void detect(const void* x, int* flag) {
  if (threadIdx.x == 0 && blockIdx.x == 0) {
    const uint32_t* xu = (const uint32_t*)x;
    int cnt = 0;
    for (int i = 0; i < 256; i++) {
      uint32_t u = xu[i];
      uint32_t ex = (u >> 23) & 0xFF;
      union { uint32_t i; float f; } c; c.i = u;
      float av = c.f < 0.f ? -c.f : c.f;
      if (ex != 0xFF && av < 1000.f) cnt++;
    }
    *flag = (cnt >= 240) ? 1 : 0;
  }
}

// -------------------------------- canonicalize small arrays (freqs + 6 vecs)
__global__ __launch_bounds__(256) void conv_arr(
    const void* s0, const void* s1, const void* s2, const void* s3,
    const void* s4, const void* s5, const void* s6,
    uint16_t* dst, const int* flag) {
  const void* srcs[7] = {s0, s1, s2, s3, s4, s5, s6};
  const int ns[7]   = {131072, 1536, 1536, 1536, 1536, 1536, 1536};
  const int offs[7] = {0, 131072, 132608, 134144, 135680, 137216, 138752};
  const int a = blockIdx.y;
  const int i = blockIdx.x * 256 + threadIdx.x;
  const int f = *flag;
  if (i < ns[a]) {
    uint16_t v = f ? f2b(((const float*)srcs[a])[i]) : ((const uint16_t*)srcs[a])[i];
    dst[offs[a] + i] = v;
  }
}

// ------------------------------------------------- transpose W (dtype-adaptive)
__global__ __launch_bounds__(256) void transposeW2(
    const void* src, uint16_t* dst, const int* flag) {
  __shared__ uint16_t t[32][33];
  const int f = *flag;
  const int bx = blockIdx.x * 32, by = blockIdx.y * 32;
  const int tx = threadIdx.x & 31, ty = threadIdx.x >> 5;  // ty 0..7
#pragma unroll
  for (int i = 0; i < 32; i += 8) {
    size_t idx = (size_t)(by + ty + i) * DIM + bx + tx;
    t[ty + i][tx] = f ? f2b(((const float*)src)[idx]) : ((const uint16_t*)src)[idx];
  }
  __syncthreads();
#pragma unroll
  for (int i = 0; i < 32; i += 8)
    dst[(size_t)(bx + ty + i) * DIM + by + tx] = t[tx][ty + i];
}

// ------------------------------------------------- GEMM: C = A * BT^T (+bias)
__global__ __launch_bounds__(256) void gemm2(
    const void* A, const uint16_t* BT, void* C, const uint16_t* bias,
    int M, int mode, int a_may_f32, int o_may_f32, const int* flag) {
  __shared__ __align__(16) uint16_t sA[128 * 32];
  __shared__ __align__(16) uint16_t sB[128 * 32];
  const int af32 = a_may_f32 && *flag;
  const int of32 = o_may_f32 && *flag;
  const int m0 = blockIdx.x * 128;
  const int n0 = blockIdx.y * 128;
  const int tid = threadIdx.x;
  const int wave = tid >> 6, lane = tid & 63;
  const int mh = (wave >> 1) * 64, nh = (wave & 1) * 64;
  const int fm = mh + (lane & 15);
  const int fn = nh + (lane & 15);
  const int ko = (lane >> 4) * 8;

  f32x4 acc[4][4];
  const f32x4 z4 = {0.f, 0.f, 0.f, 0.f};
#pragma unroll
  for (int i = 0; i < 4; i++)
#pragma unroll
    for (int j = 0; j < 4; j++) acc[i][j] = z4;

  for (int k0 = 0; k0 < DIM; k0 += 32) {
    __syncthreads();  // protect previous iteration's LDS reads
#pragma unroll
    for (int j = 0; j < 2; j++) {
      int idx = tid + j * 256;      // 0..511
      int row = idx >> 2;           // 0..127
      int cc = (idx & 3) * 8;       // 0,8,16,24
      int ra = m0 + row; ra = ra < M ? ra : M - 1;
      st8(sA + row * 32 + cc, ld8any(A, (size_t)ra * DIM + k0 + cc, af32));
      int rb = n0 + row;            // N=1536 exact multiple of 128
      st8(sB + row * 32 + cc, ld8bf(BT + (size_t)rb * DIM + k0 + cc));
    }
    __syncthreads();
    bf16x8 fa[4], fb[4];
#pragma unroll
    for (int i = 0; i < 4; i++) {
      fa[i] = ld8bf(sA + (fm + i * 16) * 32 + ko);
      fb[i] = ld8bf(sB + (fn + i * 16) * 32 + ko);
    }
#pragma unroll
    for (int i = 0; i < 4; i++)
#pragma unroll
      for (int j = 0; j < 4; j++)
        acc[i][j] = __builtin_amdgcn_mfma_f32_16x16x32_bf16(fa[i], fb[j], acc[i][j], 0, 0, 0);
  }
  // epilogue: D row=(lane>>4)*4+r, col=lane&15 (verified m89/m91)
#pragma unroll
  for (int j = 0; j < 4; j++) {
    int col = n0 + nh + j * 16 + (lane & 15);
    float bvv = (mode == 0 && bias) ? b2f(bias[col]) : 0.f;
#pragma unroll
    for (int i = 0; i < 4; i++) {
      int row = m0 + mh + i * 16 + (lane >> 4) * 4;
#pragma unroll
      for (int r = 0; r < 4; r++) {
        if (row + r < M) {
          float val = acc[i][j][r] + bvv;
          if (mode == 0) {
            if (of32) ((float*)C)[(size_t)(row + r) * DIM + col] = val;
            else ((uint16_t*)C)[(size_t)(row + r) * DIM + col] = f2b(val);
          } else {
            ((uint16_t*)C)[(size_t)(col >> 7) * ((size_t)SLEN * HD) +
                           (size_t)(row + r) * HD + (col & 127)] = f2b(val);
          }
        }
      }
    }
  }
}

// --------------------------------------- RMSNorm + gamma + 3D RoPE for Q / K
__global__ __launch_bounds__(256) void norm_rope(
    uint16_t* __restrict__ Qb, uint16_t* __restrict__ Kb,
    const uint16_t* __restrict__ bq, const uint16_t* __restrict__ bk,
    const uint16_t* __restrict__ gq, const uint16_t* __restrict__ gk,
    const uint16_t* __restrict__ freqs, const int* __restrict__ gsz) {
  const int s = blockIdx.x;
  const int isK = blockIdx.y;
  uint32_t* B = (uint32_t*)(isK ? Kb : Qb);
  const uint32_t* br = (const uint32_t*)(isK ? bk : bq);
  const uint32_t* gr = (const uint32_t*)(isK ? gk : gq);
  const int tid = threadIdx.x;
  float va[3], vb[3];
  float ss = 0.f;
#pragma unroll
  for (int i = 0; i < 3; i++) {
    int p = tid + i * 256;  // pair index 0..767 within the logical 1536-row
    int h = p >> 6, j = p & 63;
    size_t a = (size_t)h * (SLEN * 64) + (size_t)s * 64 + j;
    uint32_t u = B[a], ub = br[p];
    float x0 = b2f((uint16_t)(u & 0xffff)) + b2f((uint16_t)(ub & 0xffff));
    float x1 = b2f((uint16_t)(u >> 16)) + b2f((uint16_t)(ub >> 16));
    va[i] = x0; vb[i] = x1; ss += x0 * x0 + x1 * x1;
  }
#pragma unroll
  for (int o = 32; o > 0; o >>= 1) ss += __shfl_down(ss, o, 64);
  __shared__ float red[4];
  if ((tid & 63) == 0) red[tid >> 6] = ss;
  __syncthreads();
  ss = red[0] + red[1] + red[2] + red[3];
  const float rr = rsqrtf(ss * (1.0f / DIM) + 1e-6f);
  const int H = gsz[1], W = gsz[2];
  const int hw = H * W;
  const int fi = s / hw, rem = s - fi * hw;
  const int hi = rem / W, wi = rem - hi * W;
#pragma unroll
  for (int i = 0; i < 3; i++) {
    int p = tid + i * 256;
    int h = p >> 6, j = p & 63;
    int prow = (j < 22) ? fi : (j < 43) ? hi : wi;  // c0=22, c3=21
    uint32_t fu = ((const uint32_t*)freqs)[prow * 64 + j];
    float cs = b2f((uint16_t)(fu & 0xffff)), sn = b2f((uint16_t)(fu >> 16));
    uint32_t gu = gr[p];
    float na = va[i] * rr * b2f((uint16_t)(gu & 0xffff));
    float nb = vb[i] * rr * b2f((uint16_t)(gu >> 16));
    float ra = na * cs - nb * sn;
    float rb = na * sn + nb * cs;
    size_t a = (size_t)h * (SLEN * 64) + (size_t)s * 64 + j;
    B[a] = (uint32_t)f2b(ra) | ((uint32_t)f2b(rb) << 16);
  }
}

// ----------------- V: bias + reformat [12][SLEN][128] -> V^T [12][128][SPAD]
__global__ __launch_bounds__(256) void v_reformat(
    const uint16_t* __restrict__ Vb, const uint16_t* __restrict__ bv,
    uint16_t* __restrict__ VT) {
  __shared__ uint16_t t[128][136];
  const int head = blockIdx.x;
  const int s0 = blockIdx.y * 128;
  const int tid = threadIdx.x;
  const int cb = (tid & 15) * 8, rb = tid >> 4;
  const uint16_t* Vh = Vb + (size_t)head * SLEN * HD;
  float bvf[8];
#pragma unroll
  for (int q = 0; q < 8; q++) bvf[q] = b2f(bv[head * HD + cb + q]);
#pragma unroll
  for (int pass = 0; pass < 8; pass++) {
    int r = rb + pass * 16;
    int s = s0 + r; int sc = s < SLEN ? s : SLEN - 1;
    uint16_t u[8];
    __builtin_memcpy(u, Vh + (size_t)sc * HD + cb, 16);
#pragma unroll
    for (int q = 0; q < 8; q++) t[r][cb + q] = f2b(b2f(u[q]) + bvf[q]);
  }
  __syncthreads();
  const int sb = (tid & 15) * 8, db = tid >> 4;
#pragma unroll
  for (int pass = 0; pass < 8; pass++) {
    int d = db + pass * 16;
    uint16_t out[8] __attribute__((aligned(16)));
#pragma unroll
    for (int i2 = 0; i2 < 8; i2++) {
      int s = s0 + sb + i2;
      out[i2] = (s < SLEN) ? t[sb + i2][d] : (uint16_t)0;  // zero-fill pad cols
    }
    size_t base = ((size_t)head * HD + d) * SPAD + s0 + sb;
    if (s0 + sb + 8 <= SLEN) {
      __builtin_memcpy(VT + base, out, 16);
    } else {
#pragma unroll
      for (int i2 = 0; i2 < 8; i2++) {
        int s = s0 + sb + i2;
        if (s < SPAD) VT[base + i2] = out[i2];
      }
    }
  }
}

// ------------------------------------------------ flash attention (bf16 MFMA)
// R4 structure exactly (sQ buffer, in-loop Q fragment reads, 3 barriers/iter)
// + ONLY change: padded LDS row strides to break the 128B bank period.
__global__ __launch_bounds__(256) void attn(
    const uint16_t* __restrict__ Q, const uint16_t* __restrict__ K,
    const uint16_t* __restrict__ VT, uint16_t* __restrict__ O,
    const int* __restrict__ seq_lens) {
  __shared__ __align__(16) uint16_t sQ[64 * SKP];  // [q][d]
  __shared__ __align__(16) uint16_t sK[64 * SKP];  // [kk][d]
  __shared__ __align__(16) uint16_t sV[128 * SVP]; // [d][kk]  (from V^T)
  __shared__ __align__(16) uint16_t sP[64 * SVP];  // [q][kk]
  const int head = blockIdx.x;
  const int q0 = blockIdx.y * 64;
  const int tid = threadIdx.x;
  const int wave = tid >> 6, lane = tid & 63;
  int sl = seq_lens[0];
  const int seqlen = sl < SLEN ? sl : SLEN;
  const uint16_t* Qh = Q + (size_t)head * SLEN * HD;
  const uint16_t* Kh = K + (size_t)head * SLEN * HD;
  const uint16_t* Vh = VT + (size_t)head * HD * SPAD;

  // stage Q tile once: 64 rows x 128 cols
#pragma unroll
  for (int ps = 0; ps < 4; ps++) {
    int idx = tid + ps * 256;
    int row = idx >> 4, cc = (idx & 15) * 8;
    int qg = q0 + row; qg = qg < SLEN ? qg : SLEN - 1;
    st8(sQ + row * SKP + cc, ld8bf(Qh + (size_t)qg * HD + cc));
  }
  __syncthreads();

  f32x4 o[8];
  const f32x4 z4 = {0.f, 0.f, 0.f, 0.f};
#pragma unroll
  for (int j = 0; j < 8; j++) o[j] = z4;
  float m_r[4] = {-3.0e38f, -3.0e38f, -3.0e38f, -3.0e38f};
  float l_r[4] = {0.f, 0.f, 0.f, 0.f};

  const int fm = lane & 15;
  const int ko = (lane >> 4) * 8;
  const float scale = 0.08838834764831845f;  // 1/sqrt(128)
  const float LOG2E = 1.4426950408889634f;

  for (int kv0 = 0; kv0 < SLEN; kv0 += 64) {
    __syncthreads();
    // stage K: 64 rows x 128 cols
#pragma unroll
    for (int ps = 0; ps < 4; ps++) {
      int idx = tid + ps * 256;
      int row = idx >> 4, cc = (idx & 15) * 8;
      int kg = kv0 + row; kg = kg < SLEN ? kg : SLEN - 1;
      st8(sK + row * SKP + cc, ld8bf(Kh + (size_t)kg * HD + cc));
    }
    // stage V^T: 128 rows(d) x 64 cols(kv)
#pragma unroll
    for (int ps = 0; ps < 4; ps++) {
      int idx = tid + ps * 256;
      int d = idx >> 3, cc = (idx & 7) * 8;
      st8(sV + d * SVP + cc, ld8bf(Vh + (size_t)d * SPAD + kv0 + cc));
    }
    __syncthreads();

    // QK^T : 16 mfma
    f32x4 sc[4];
#pragma unroll
    for (int kk = 0; kk < 4; kk++) sc[kk] = z4;
#pragma unroll
    for (int kc = 0; kc < 4; kc++) {
      bf16x8 aq = ld8bf(sQ + (wave * 16 + fm) * SKP + kc * 32 + ko);
#pragma unroll
      for (int kk = 0; kk < 4; kk++) {
        bf16x8 bkf = ld8bf(sK + (kk * 16 + fm) * SKP + kc * 32 + ko);
        sc[kk] = __builtin_amdgcn_mfma_f32_16x16x32_bf16(aq, bkf, sc[kk], 0, 0, 0);
      }
    }
    // scale + key mask
#pragma unroll
    for (int kk = 0; kk < 4; kk++) {
      int col = kv0 + kk * 16 + fm;
      bool valid = col < seqlen;
#pragma unroll
      for (int r = 0; r < 4; r++)
        sc[kk][r] = valid ? sc[kk][r] * scale : -3.0e38f;
    }
    // online softmax (rows live in 16-lane groups; butterfly over lane&15)
    float pv[4][4];
#pragma unroll
    for (int r = 0; r < 4; r++) {
      float v = fmaxf(fmaxf(sc[0][r], sc[1][r]), fmaxf(sc[2][r], sc[3][r]));
#pragma unroll
      for (int off = 1; off < 16; off <<= 1) v = fmaxf(v, __shfl_xor(v, off, 64));
      float mnew = fmaxf(m_r[r], v);
      float al = exp2f((m_r[r] - mnew) * LOG2E);
      float sum = 0.f;
#pragma unroll
      for (int kk = 0; kk < 4; kk++) {
        float p = exp2f((sc[kk][r] - mnew) * LOG2E);
        pv[kk][r] = p; sum += p;
      }
#pragma unroll
      for (int off = 1; off < 16; off <<= 1) sum += __shfl_xor(sum, off, 64);
      l_r[r] = l_r[r] * al + sum;
      m_r[r] = mnew;
#pragma unroll
      for (int j = 0; j < 8; j++) o[j][r] *= al;
    }
    // P: C-layout -> A-layout via LDS round trip (m120 pattern)
#pragma unroll
    for (int kk = 0; kk < 4; kk++)
#pragma unroll
      for (int r = 0; r < 4; r++)
        sP[(wave * 16 + (lane >> 4) * 4 + r) * SVP + kk * 16 + fm] = f2b(pv[kk][r]);
    __syncthreads();
    // PV : 16 mfma
#pragma unroll
    for (int kc = 0; kc < 2; kc++) {
      bf16x8 ap = ld8bf(sP + (wave * 16 + fm) * SVP + kc * 32 + ko);
#pragma unroll
      for (int j = 0; j < 8; j++) {
        bf16x8 bvf = ld8bf(sV + (j * 16 + fm) * SVP + kc * 32 + ko);
        o[j] = __builtin_amdgcn_mfma_f32_16x16x32_bf16(ap, bvf, o[j], 0, 0, 0);
      }
    }
  }
  // epilogue: normalize and write [s][head*128+d]
#pragma unroll
  for (int r = 0; r < 4; r++) {
    int row = q0 + wave * 16 + (lane >> 4) * 4 + r;
    if (row < SLEN) {
      float inv = 1.0f / l_r[r];
#pragma unroll
      for (int j = 0; j < 8; j++) {
        int col = head * HD + j * 16 + fm;
        O[(size_t)row * DIM + col] = f2b(o[j][r] * inv);
      }
    }
  }
}

// ----------------------------------------------------------------- launcher
extern "C" void kernel_launch(void* const* d_in, const int* in_sizes, int n_in,
                              void* d_out, int out_size, void* d_ws, size_t ws_size,
                              hipStream_t stream) {
  const void* x     = d_in[0];
  const int* seq_lens = (const int*)d_in[1];
  const int* gsz      = (const int*)d_in[2];
  const void* freqs = d_in[3];
  const void* Wq    = d_in[4];
  const void* bq    = d_in[5];
  const void* Wk    = d_in[6];
  const void* bk    = d_in[7];
  const void* Wv    = d_in[8];
  const void* bv    = d_in[9];
  const void* Wo    = d_in[10];
  const void* bo    = d_in[11];
  const void* gq    = d_in[12];
  const void* gk    = d_in[13];

  // workspace layout (~53 MB)
  char* p = (char*)d_ws;
  int* flag = (int*)p;          p += 256;
  uint16_t* vec = (uint16_t*)p; p += 140288 * 2 + 256;             // 0.28 MB
  uint16_t* WT  = (uint16_t*)p; p += (size_t)DIM * DIM * 2;        // 4.72 MB
  uint16_t* Qb  = (uint16_t*)p; p += (size_t)NH * SLEN * HD * 2;   // 11.98 MB
  uint16_t* Kb  = (uint16_t*)p; p += (size_t)NH * SLEN * HD * 2;   // 11.98 MB
  uint16_t* Vb  = (uint16_t*)p; p += (size_t)NH * SLEN * HD * 2;   // 11.98 MB
  uint16_t* VTb = (uint16_t*)p; p += (size_t)NH * HD * SPAD * 2;   // 11.99 MB
  uint16_t* AO  = Vb;  // attn reads VTb/Qb/Kb only; Vb free by then

  uint16_t* freqsC = vec;
  uint16_t* bqC = vec + 131072;
  uint16_t* bkC = bqC + 1536;
  uint16_t* bvC = bkC + 1536;
  uint16_t* boC = bvC + 1536;
  uint16_t* gqC = boC + 1536;
  uint16_t* gkC = gqC + 1536;

  detect<<<1, 64, 0, stream>>>(x, flag);
  conv_arr<<<dim3(512, 7), 256, 0, stream>>>(freqs, bq, bk, bv, bo, gq, gk, vec, flag);

  transposeW2<<<dim3(48, 48), 256, 0, stream>>>(Wq, WT, flag);
  gemm2<<<dim3(31, 12), 256, 0, stream>>>(x, WT, Qb, nullptr, SLEN, 1, 1, 0, flag);
  transposeW2<<<dim3(48, 48), 256, 0, stream>>>(Wk, WT, flag);
  gemm2<<<dim3(31, 12), 256, 0, stream>>>(x, WT, Kb, nullptr, SLEN, 1, 1, 0, flag);
  transposeW2<<<dim3(48, 48), 256, 0, stream>>>(Wv, WT, flag);
  gemm2<<<dim3(31, 12), 256, 0, stream>>>(x, WT, Vb, nullptr, SLEN, 1, 1, 0, flag);

  norm_rope<<<dim3(SLEN, 2), 256, 0, stream>>>(Qb, Kb, bqC, bkC, gqC, gkC, freqsC, gsz);
  v_reformat<<<dim3(NH, 31), 256, 0, stream>>>(Vb, bvC, VTb);
  attn<<<dim3(NH, 61), 256, 0, stream>>>(Qb, Kb, VTb, AO, seq_lens);

  transposeW2<<<dim3(48, 48), 256, 0, stream>>>(Wo, WT, flag);
  gemm2<<<dim3(31, 12), 256, 0, stream>>>(AO, WT, d_out, boC, SLEN, 0, 0, 1, flag);
}

// Round 8
// 737.632 us; speedup vs baseline: 1.3008x; 1.0737x over previous
//
#include <hip/hip_runtime.h>
#include <stdint.h>

// Inputs are FP32 (proven R4-R7 pass/fail matrix); output is FP32.
#define DIM 1536
#define SLEN 3900
#define SPAD 3904   // padded V^T row stride (16B-aligned rows)
#define NH 12
#define HD 128
#define SKP 136     // sK row stride (elems): 272B pitch breaks 128B bank period
#define SVP 68      // sV/sP row stride (elems): 136B pitch (2 banks/row shift)
#define SGP 40      // gemm sA/sB row stride: 80B pitch

typedef __bf16 bf16x8 __attribute__((ext_vector_type(8)));
typedef float f32x4 __attribute__((ext_vector_type(4)));

__device__ __forceinline__ float b2f(uint16_t u) {
  union { uint32_t i; float f; } x; x.i = ((uint32_t)u) << 16; return x.f;
}
__device__ __forceinline__ uint16_t f2b(float f) {
  union { float f; uint32_t i; } x; x.f = f;
  uint32_t r = (x.i + 0x7fffu + ((x.i >> 16) & 1u)) >> 16;
  return (uint16_t)r;
}
__device__ __forceinline__ bf16x8 ld8bf(const uint16_t* p) {
  bf16x8 r; __builtin_memcpy(&r, p, 16); return r;
}
__device__ __forceinline__ void st8(uint16_t* p, bf16x8 v) {
  __builtin_memcpy(p, &v, 16);
}

// ------------------------------------------------ x: fp32 -> bf16 (one pass)
__global__ __launch_bounds__(256) void conv_x(
    const float* __restrict__ x, uint16_t* __restrict__ xb) {
  int i = (blockIdx.x * 256 + threadIdx.x) * 8;  // n divisible by 8
  float a[8];
  __builtin_memcpy(a, x + i, 32);
  uint16_t t[8];
#pragma unroll
  for (int q = 0; q < 8; q++) t[q] = f2b(a[q]);
  __builtin_memcpy(xb + i, t, 16);
}

// ------------------------------------- transpose W: fp32 in -> bf16^T out
__global__ __launch_bounds__(256) void transposeWf(
    const float* __restrict__ src, uint16_t* __restrict__ dst) {
  __shared__ uint16_t t[32][33];
  const int bx = blockIdx.x * 32, by = blockIdx.y * 32;
  const int tx = threadIdx.x & 31, ty = threadIdx.x >> 5;  // ty 0..7
#pragma unroll
  for (int i = 0; i < 32; i += 8)
    t[ty + i][tx] = f2b(src[(size_t)(by + ty + i) * DIM + bx + tx]);
  __syncthreads();
#pragma unroll
  for (int i = 0; i < 32; i += 8)
    dst[(size_t)(bx + ty + i) * DIM + by + tx] = t[tx][ty + i];
}

// ------------------------------------------------- GEMM: C = A * BT^T (+bias)
// A [M][DIM] bf16; BT bf16. mode 0: C fp32 [M][DIM] + fp32 bias.
// mode 1: head-split C [12][SLEN][128] bf16. 128x128 tile, BK=32, 4 waves.
__global__ __launch_bounds__(256) void gemm(
    const uint16_t* __restrict__ A, const uint16_t* __restrict__ BT,
    void* __restrict__ C, const float* __restrict__ bias, int M, int mode) {
  __shared__ __align__(16) uint16_t sA[128 * SGP];
  __shared__ __align__(16) uint16_t sB[128 * SGP];
  const int m0 = blockIdx.x * 128;
  const int n0 = blockIdx.y * 128;
  const int tid = threadIdx.x;
  const int wave = tid >> 6, lane = tid & 63;
  const int mh = (wave >> 1) * 64, nh = (wave & 1) * 64;
  const int fm = mh + (lane & 15);
  const int fn = nh + (lane & 15);
  const int ko = (lane >> 4) * 8;

  f32x4 acc[4][4];
  const f32x4 z4 = {0.f, 0.f, 0.f, 0.f};
#pragma unroll
  for (int i = 0; i < 4; i++)
#pragma unroll
    for (int j = 0; j < 4; j++) acc[i][j] = z4;

  for (int k0 = 0; k0 < DIM; k0 += 32) {
    __syncthreads();
#pragma unroll
    for (int j = 0; j < 2; j++) {
      int idx = tid + j * 256;      // 0..511
      int row = idx >> 2;           // 0..127
      int cc = (idx & 3) * 8;       // 0,8,16,24
      int ra = m0 + row; ra = ra < M ? ra : M - 1;
      st8(sA + row * SGP + cc, ld8bf(A + (size_t)ra * DIM + k0 + cc));
      int rb = n0 + row;
      st8(sB + row * SGP + cc, ld8bf(BT + (size_t)rb * DIM + k0 + cc));
    }
    __syncthreads();
    bf16x8 fa[4], fb[4];
#pragma unroll
    for (int i = 0; i < 4; i++) {
      fa[i] = ld8bf(sA + (fm + i * 16) * SGP + ko);
      fb[i] = ld8bf(sB + (fn + i * 16) * SGP + ko);
    }
#pragma unroll
    for (int i = 0; i < 4; i++)
#pragma unroll
      for (int j = 0; j < 4; j++)
        acc[i][j] = __builtin_amdgcn_mfma_f32_16x16x32_bf16(fa[i], fb[j], acc[i][j], 0, 0, 0);
  }
  // epilogue: D row=(lane>>4)*4+r, col=lane&15
#pragma unroll
  for (int j = 0; j < 4; j++) {
    int col = n0 + nh + j * 16 + (lane & 15);
    float bvv = (mode == 0 && bias) ? bias[col] : 0.f;
#pragma unroll
    for (int i = 0; i < 4; i++) {
      int row = m0 + mh + i * 16 + (lane >> 4) * 4;
#pragma unroll
      for (int r = 0; r < 4; r++) {
        if (row + r < M) {
          float val = acc[i][j][r] + bvv;
          if (mode == 0)
            ((float*)C)[(size_t)(row + r) * DIM + col] = val;
          else
            ((uint16_t*)C)[(size_t)(col >> 7) * ((size_t)SLEN * HD) +
                           (size_t)(row + r) * HD + (col & 127)] = f2b(val);
        }
      }
    }
  }
}

// --------------------------------------- RMSNorm + gamma + 3D RoPE for Q / K
// In/out (in-place): Qb/Kb head-split [12][SLEN][128] bf16. Params fp32.
__global__ __launch_bounds__(256) void norm_rope(
    uint16_t* __restrict__ Qb, uint16_t* __restrict__ Kb,
    const float* __restrict__ bq, const float* __restrict__ bk,
    const float* __restrict__ gq, const float* __restrict__ gk,
    const float* __restrict__ freqs, const int* __restrict__ gsz) {
  const int s = blockIdx.x;
  const int isK = blockIdx.y;
  uint32_t* B = (uint32_t*)(isK ? Kb : Qb);
  const float2* br = (const float2*)(isK ? bk : bq);
  const float2* gr = (const float2*)(isK ? gk : gq);
  const int tid = threadIdx.x;
  float va[3], vb[3];
  float ss = 0.f;
#pragma unroll
  for (int i = 0; i < 3; i++) {
    int p = tid + i * 256;  // pair index 0..767
    int h = p >> 6, j = p & 63;
    size_t a = (size_t)h * (SLEN * 64) + (size_t)s * 64 + j;
    uint32_t u = B[a];
    float2 ub = br[p];
    float x0 = b2f((uint16_t)(u & 0xffff)) + ub.x;
    float x1 = b2f((uint16_t)(u >> 16)) + ub.y;
    va[i] = x0; vb[i] = x1; ss += x0 * x0 + x1 * x1;
  }
#pragma unroll
  for (int o = 32; o > 0; o >>= 1) ss += __shfl_down(ss, o, 64);
  __shared__ float red[4];
  if ((tid & 63) == 0) red[tid >> 6] = ss;
  __syncthreads();
  ss = red[0] + red[1] + red[2] + red[3];
  const float rr = rsqrtf(ss * (1.0f / DIM) + 1e-6f);
  const int H = gsz[1], W = gsz[2];
  const int hw = H * W;
  const int fi = s / hw, rem = s - fi * hw;
  const int hi = rem / W, wi = rem - hi * W;
#pragma unroll
  for (int i = 0; i < 3; i++) {
    int p = tid + i * 256;
    int h = p >> 6, j = p & 63;
    int prow = (j < 22) ? fi : (j < 43) ? hi : wi;  // c0=22, c3=21
    float2 f2 = ((const float2*)freqs)[prow * 64 + j];
    float2 g2 = gr[p];
    float na = va[i] * rr * g2.x;
    float nb = vb[i] * rr * g2.y;
    float ra = na * f2.x - nb * f2.y;
    float rb = na * f2.y + nb * f2.x;
    size_t a = (size_t)h * (SLEN * 64) + (size_t)s * 64 + j;
    B[a] = (uint32_t)f2b(ra) | ((uint32_t)f2b(rb) << 16);
  }
}

// ----------------- V: bias(fp32) + reformat [12][SLEN][128] -> V^T [12][128][SPAD]
__global__ __launch_bounds__(256) void v_reformat(
    const uint16_t* __restrict__ Vb, const float* __restrict__ bv,
    uint16_t* __restrict__ VT) {
  __shared__ uint16_t t[128][136];
  const int head = blockIdx.x;
  const int s0 = blockIdx.y * 128;
  const int tid = threadIdx.x;
  const int cb = (tid & 15) * 8, rb = tid >> 4;
  const uint16_t* Vh = Vb + (size_t)head * SLEN * HD;
  float bvf[8];
#pragma unroll
  for (int q = 0; q < 8; q++) bvf[q] = bv[head * HD + cb + q];
#pragma unroll
  for (int pass = 0; pass < 8; pass++) {
    int r = rb + pass * 16;
    int s = s0 + r; int sc = s < SLEN ? s : SLEN - 1;
    uint16_t u[8];
    __builtin_memcpy(u, Vh + (size_t)sc * HD + cb, 16);
#pragma unroll
    for (int q = 0; q < 8; q++) t[r][cb + q] = f2b(b2f(u[q]) + bvf[q]);
  }
  __syncthreads();
  const int sb = (tid & 15) * 8, db = tid >> 4;
#pragma unroll
  for (int pass = 0; pass < 8; pass++) {
    int d = db + pass * 16;
    uint16_t out[8] __attribute__((aligned(16)));
#pragma unroll
    for (int i2 = 0; i2 < 8; i2++) {
      int s = s0 + sb + i2;
      out[i2] = (s < SLEN) ? t[sb + i2][d] : (uint16_t)0;
    }
    size_t base = ((size_t)head * HD + d) * SPAD + s0 + sb;
    if (s0 + sb + 8 <= SLEN) {
      __builtin_memcpy(VT + base, out, 16);
    } else {
#pragma unroll
      for (int i2 = 0; i2 < 8; i2++) {
        int s = s0 + sb + i2;
        if (s < SPAD) VT[base + i2] = out[i2];
      }
    }
  }
}

// ------------------------------------------------ flash attention (bf16 MFMA)
// grid (12 heads, 31 q-tiles of 128); 4 waves; wave owns 32 q rows (2 tiles).
// Q fragments in registers; padded LDS strides; 3 barriers/iter.
__global__ __launch_bounds__(256) void attn(
    const uint16_t* __restrict__ Q, const uint16_t* __restrict__ K,
    const uint16_t* __restrict__ VT, uint16_t* __restrict__ O,
    const int* __restrict__ seq_lens) {
  __shared__ __align__(16) uint16_t sK[64 * SKP];   // [kk][d]  17.0 KB
  __shared__ __align__(16) uint16_t sV[128 * SVP];  // [d][kk]  17.0 KB
  __shared__ __align__(16) uint16_t sP[128 * SVP];  // [q][kk]  17.0 KB
  const int head = blockIdx.x;
  const int q0 = blockIdx.y * 128;
  const int tid = threadIdx.x;
  const int wave = tid >> 6, lane = tid & 63;
  int sl = seq_lens[0];
  const int seqlen = sl < SLEN ? sl : SLEN;
  const uint16_t* Qh = Q + (size_t)head * SLEN * HD;
  const uint16_t* Kh = K + (size_t)head * SLEN * HD;
  const uint16_t* Vh = VT + (size_t)head * HD * SPAD;

  const int fm = lane & 15;
  const int ko = (lane >> 4) * 8;

  // stage Q through sK in two 64-row rounds; pull fragments to registers
  bf16x8 aq[2][4];
#pragma unroll
  for (int round = 0; round < 2; round++) {
#pragma unroll
    for (int ps = 0; ps < 4; ps++) {
      int idx = tid + ps * 256;
      int row = idx >> 4, cc = (idx & 15) * 8;
      int qg = q0 + round * 64 + row; qg = qg < SLEN ? qg : SLEN - 1;
      st8(sK + row * SKP + cc, ld8bf(Qh + (size_t)qg * HD + cc));
    }
    __syncthreads();
    if ((wave >> 1) == round) {
      int lw = wave & 1;
#pragma unroll
      for (int qt = 0; qt < 2; qt++)
#pragma unroll
        for (int kc = 0; kc < 4; kc++)
          aq[qt][kc] = ld8bf(sK + (lw * 32 + qt * 16 + fm) * SKP + kc * 32 + ko);
    }
    __syncthreads();
  }

  f32x4 o[2][8];
  const f32x4 z4 = {0.f, 0.f, 0.f, 0.f};
#pragma unroll
  for (int qt = 0; qt < 2; qt++)
#pragma unroll
    for (int j = 0; j < 8; j++) o[qt][j] = z4;
  float m_r[2][4], l_r[2][4];
#pragma unroll
  for (int qt = 0; qt < 2; qt++)
#pragma unroll
    for (int r = 0; r < 4; r++) { m_r[qt][r] = -3.0e38f; l_r[qt][r] = 0.f; }

  const float scale = 0.08838834764831845f;  // 1/sqrt(128)
  const float LOG2E = 1.4426950408889634f;

  for (int kv0 = 0; kv0 < SLEN; kv0 += 64) {
    __syncthreads();
    // stage K: 64 rows x 128 cols
#pragma unroll
    for (int ps = 0; ps < 4; ps++) {
      int idx = tid + ps * 256;
      int row = idx >> 4, cc = (idx & 15) * 8;
      int kg = kv0 + row; kg = kg < SLEN ? kg : SLEN - 1;
      st8(sK + row * SKP + cc, ld8bf(Kh + (size_t)kg * HD + cc));
    }
    // stage V^T: 128 rows(d) x 64 cols(kv)
#pragma unroll
    for (int ps = 0; ps < 4; ps++) {
      int idx = tid + ps * 256;
      int d = idx >> 3, cc = (idx & 7) * 8;
      st8(sV + d * SVP + cc, ld8bf(Vh + (size_t)d * SPAD + kv0 + cc));
    }
    __syncthreads();

    // QK^T : 32 mfma (two q-tiles share each K fragment)
    f32x4 sc[2][4];
#pragma unroll
    for (int qt = 0; qt < 2; qt++)
#pragma unroll
      for (int kk = 0; kk < 4; kk++) sc[qt][kk] = z4;
#pragma unroll
    for (int kc = 0; kc < 4; kc++) {
#pragma unroll
      for (int kk = 0; kk < 4; kk++) {
        bf16x8 bkf = ld8bf(sK + (kk * 16 + fm) * SKP + kc * 32 + ko);
        sc[0][kk] = __builtin_amdgcn_mfma_f32_16x16x32_bf16(aq[0][kc], bkf, sc[0][kk], 0, 0, 0);
        sc[1][kk] = __builtin_amdgcn_mfma_f32_16x16x32_bf16(aq[1][kc], bkf, sc[1][kk], 0, 0, 0);
      }
    }
    // scale + key mask + online softmax; write P straight to sP
#pragma unroll
    for (int qt = 0; qt < 2; qt++) {
#pragma unroll
      for (int kk = 0; kk < 4; kk++) {
        int col = kv0 + kk * 16 + fm;
        bool valid = col < seqlen;
#pragma unroll
        for (int r = 0; r < 4; r++)
          sc[qt][kk][r] = valid ? sc[qt][kk][r] * scale : -3.0e38f;
      }
#pragma unroll
      for (int r = 0; r < 4; r++) {
        float v = fmaxf(fmaxf(sc[qt][0][r], sc[qt][1][r]),
                        fmaxf(sc[qt][2][r], sc[qt][3][r]));
#pragma unroll
        for (int off = 1; off < 16; off <<= 1) v = fmaxf(v, __shfl_xor(v, off, 64));
        float mnew = fmaxf(m_r[qt][r], v);
        float al = exp2f((m_r[qt][r] - mnew) * LOG2E);
        float sum = 0.f;
        int prow = (wave * 32 + qt * 16 + (lane >> 4) * 4 + r) * SVP + fm;
#pragma unroll
        for (int kk = 0; kk < 4; kk++) {
          float p = exp2f((sc[qt][kk][r] - mnew) * LOG2E);
          sum += p;
          sP[prow + kk * 16] = f2b(p);
        }
#pragma unroll
        for (int off = 1; off < 16; off <<= 1) sum += __shfl_xor(sum, off, 64);
        l_r[qt][r] = l_r[qt][r] * al + sum;
        m_r[qt][r] = mnew;
#pragma unroll
        for (int j = 0; j < 8; j++) o[qt][j][r] *= al;
      }
    }
    __syncthreads();
    // PV : 32 mfma (two q-tiles share each V fragment)
#pragma unroll
    for (int kc = 0; kc < 2; kc++) {
      bf16x8 ap0 = ld8bf(sP + (wave * 32 + fm) * SVP + kc * 32 + ko);
      bf16x8 ap1 = ld8bf(sP + (wave * 32 + 16 + fm) * SVP + kc * 32 + ko);
#pragma unroll
      for (int j = 0; j < 8; j++) {
        bf16x8 bvf = ld8bf(sV + (j * 16 + fm) * SVP + kc * 32 + ko);
        o[0][j] = __builtin_amdgcn_mfma_f32_16x16x32_bf16(ap0, bvf, o[0][j], 0, 0, 0);
        o[1][j] = __builtin_amdgcn_mfma_f32_16x16x32_bf16(ap1, bvf, o[1][j], 0, 0, 0);
      }
    }
  }
  // epilogue: normalize and write [s][head*128+d] (bf16 internal buffer)
#pragma unroll
  for (int qt = 0; qt < 2; qt++)
#pragma unroll
    for (int r = 0; r < 4; r++) {
      int row = q0 + wave * 32 + qt * 16 + (lane >> 4) * 4 + r;
      if (row < SLEN) {
        float inv = 1.0f / l_r[qt][r];
#pragma unroll
        for (int j = 0; j < 8; j++) {
          int col = head * HD + j * 16 + fm;
          O[(size_t)row * DIM + col] = f2b(o[qt][j][r] * inv);
        }
      }
    }
}

// ----------------------------------------------------------------- launcher
extern "C" void kernel_launch(void* const* d_in, const int* in_sizes, int n_in,
                              void* d_out, int out_size, void* d_ws, size_t ws_size,
                              hipStream_t stream) {
  const float* x      = (const float*)d_in[0];
  const int* seq_lens = (const int*)d_in[1];
  const int* gsz      = (const int*)d_in[2];
  const float* freqs  = (const float*)d_in[3];
  const float* Wq     = (const float*)d_in[4];
  const float* bq     = (const float*)d_in[5];
  const float* Wk     = (const float*)d_in[6];
  const float* bk     = (const float*)d_in[7];
  const float* Wv     = (const float*)d_in[8];
  const float* bv     = (const float*)d_in[9];
  const float* Wo     = (const float*)d_in[10];
  const float* bo     = (const float*)d_in[11];
  const float* gq     = (const float*)d_in[12];
  const float* gk     = (const float*)d_in[13];

  // workspace (~53 MB): xb aliases VTb (x consumed by gemms before v_reformat)
  char* p = (char*)d_ws;
  uint16_t* WT  = (uint16_t*)p; p += (size_t)DIM * DIM * 2;        //  4.72 MB
  uint16_t* Qb  = (uint16_t*)p; p += (size_t)NH * SLEN * HD * 2;   // 11.98 MB
  uint16_t* Kb  = (uint16_t*)p; p += (size_t)NH * SLEN * HD * 2;   // 11.98 MB
  uint16_t* Vb  = (uint16_t*)p; p += (size_t)NH * SLEN * HD * 2;   // 11.98 MB
  uint16_t* VTb = (uint16_t*)p; p += (size_t)NH * HD * SPAD * 2;   // 11.99 MB
  uint16_t* xb  = VTb;   // [SLEN][DIM] bf16 (11.98 MB) — dead before VTb written
  uint16_t* AO  = Vb;    // attn output overlays Vb (consumed by v_reformat)

  conv_x<<<dim3(2925), 256, 0, stream>>>(x, xb);

  transposeWf<<<dim3(48, 48), 256, 0, stream>>>(Wq, WT);
  gemm<<<dim3(31, 12), 256, 0, stream>>>(xb, WT, Qb, nullptr, SLEN, 1);
  transposeWf<<<dim3(48, 48), 256, 0, stream>>>(Wk, WT);
  gemm<<<dim3(31, 12), 256, 0, stream>>>(xb, WT, Kb, nullptr, SLEN, 1);
  transposeWf<<<dim3(48, 48), 256, 0, stream>>>(Wv, WT);
  gemm<<<dim3(31, 12), 256, 0, stream>>>(xb, WT, Vb, nullptr, SLEN, 1);

  norm_rope<<<dim3(SLEN, 2), 256, 0, stream>>>(Qb, Kb, bq, bk, gq, gk, freqs, gsz);
  v_reformat<<<dim3(NH, 31), 256, 0, stream>>>(Vb, bv, VTb);
  attn<<<dim3(NH, 31), 256, 0, stream>>>(Qb, Kb, VTb, AO, seq_lens);

  transposeWf<<<dim3(48, 48), 256, 0, stream>>>(Wo, WT);
  gemm<<<dim3(31, 12), 256, 0, stream>>>(AO, WT, d_out, bo, SLEN, 0);
}

// Round 9
// 594.021 us; speedup vs baseline: 1.6152x; 1.2418x over previous
//
#include <hip/hip_runtime.h>
#include <stdint.h>

// Inputs are FP32 (proven R4-R7 pass/fail matrix); output is FP32.
#define DIM 1536
#define SLEN 3900
#define SPAD 3904   // padded V^T row stride (16B-aligned rows)
#define NH 12
#define HD 128
#define SKP 136     // sK row stride (elems): 272B pitch breaks 128B bank period
#define SVP 68      // sV/sP row stride (elems): 136B pitch
#define SGP 40      // gemm sA/sB row stride: 80B pitch

typedef __bf16 bf16x8 __attribute__((ext_vector_type(8)));
typedef float f32x4 __attribute__((ext_vector_type(4)));

__device__ __forceinline__ float b2f(uint16_t u) {
  union { uint32_t i; float f; } x; x.i = ((uint32_t)u) << 16; return x.f;
}
__device__ __forceinline__ uint16_t f2b(float f) {
  union { float f; uint32_t i; } x; x.f = f;
  uint32_t r = (x.i + 0x7fffu + ((x.i >> 16) & 1u)) >> 16;
  return (uint16_t)r;
}
__device__ __forceinline__ bf16x8 ld8bf(const uint16_t* p) {
  bf16x8 r; __builtin_memcpy(&r, p, 16); return r;
}
__device__ __forceinline__ void st8(uint16_t* p, bf16x8 v) {
  __builtin_memcpy(p, &v, 16);
}

// ------------------------------------------------ x: fp32 -> bf16 (one pass)
__global__ __launch_bounds__(256) void conv_x(
    const float* __restrict__ x, uint16_t* __restrict__ xb) {
  int i = (blockIdx.x * 256 + threadIdx.x) * 8;  // n divisible by 8
  float a[8];
  __builtin_memcpy(a, x + i, 32);
  uint16_t t[8];
#pragma unroll
  for (int q = 0; q < 8; q++) t[q] = f2b(a[q]);
  __builtin_memcpy(xb + i, t, 16);
}

// ------------------------------------- transpose W: fp32 in -> bf16^T out
__global__ __launch_bounds__(256) void transposeWf(
    const float* __restrict__ src, uint16_t* __restrict__ dst) {
  __shared__ uint16_t t[32][33];
  const int bx = blockIdx.x * 32, by = blockIdx.y * 32;
  const int tx = threadIdx.x & 31, ty = threadIdx.x >> 5;  // ty 0..7
#pragma unroll
  for (int i = 0; i < 32; i += 8)
    t[ty + i][tx] = f2b(src[(size_t)(by + ty + i) * DIM + bx + tx]);
  __syncthreads();
#pragma unroll
  for (int i = 0; i < 32; i += 8)
    dst[(size_t)(bx + ty + i) * DIM + by + tx] = t[tx][ty + i];
}

// ------------------------------------------------- GEMM: C = A * BT^T (+bias)
// A [M][DIM] bf16; BT bf16. mode 0: C fp32 [M][DIM] + fp32 bias.
// mode 1: head-split C [12][SLEN][128] bf16. 128x128 tile, BK=32, 4 waves.
__global__ __launch_bounds__(256) void gemm(
    const uint16_t* __restrict__ A, const uint16_t* __restrict__ BT,
    void* __restrict__ C, const float* __restrict__ bias, int M, int mode) {
  __shared__ __align__(16) uint16_t sA[128 * SGP];
  __shared__ __align__(16) uint16_t sB[128 * SGP];
  const int m0 = blockIdx.x * 128;
  const int n0 = blockIdx.y * 128;
  const int tid = threadIdx.x;
  const int wave = tid >> 6, lane = tid & 63;
  const int mh = (wave >> 1) * 64, nh = (wave & 1) * 64;
  const int fm = mh + (lane & 15);
  const int fn = nh + (lane & 15);
  const int ko = (lane >> 4) * 8;

  f32x4 acc[4][4];
  const f32x4 z4 = {0.f, 0.f, 0.f, 0.f};
#pragma unroll
  for (int i = 0; i < 4; i++)
#pragma unroll
    for (int j = 0; j < 4; j++) acc[i][j] = z4;

  for (int k0 = 0; k0 < DIM; k0 += 32) {
    __syncthreads();
#pragma unroll
    for (int j = 0; j < 2; j++) {
      int idx = tid + j * 256;      // 0..511
      int row = idx >> 2;           // 0..127
      int cc = (idx & 3) * 8;       // 0,8,16,24
      int ra = m0 + row; ra = ra < M ? ra : M - 1;
      st8(sA + row * SGP + cc, ld8bf(A + (size_t)ra * DIM + k0 + cc));
      int rb = n0 + row;
      st8(sB + row * SGP + cc, ld8bf(BT + (size_t)rb * DIM + k0 + cc));
    }
    __syncthreads();
    bf16x8 fa[4], fb[4];
#pragma unroll
    for (int i = 0; i < 4; i++) {
      fa[i] = ld8bf(sA + (fm + i * 16) * SGP + ko);
      fb[i] = ld8bf(sB + (fn + i * 16) * SGP + ko);
    }
#pragma unroll
    for (int i = 0; i < 4; i++)
#pragma unroll
      for (int j = 0; j < 4; j++)
        acc[i][j] = __builtin_amdgcn_mfma_f32_16x16x32_bf16(fa[i], fb[j], acc[i][j], 0, 0, 0);
  }
  // epilogue: D row=(lane>>4)*4+r, col=lane&15
#pragma unroll
  for (int j = 0; j < 4; j++) {
    int col = n0 + nh + j * 16 + (lane & 15);
    float bvv = (mode == 0 && bias) ? bias[col] : 0.f;
#pragma unroll
    for (int i = 0; i < 4; i++) {
      int row = m0 + mh + i * 16 + (lane >> 4) * 4;
#pragma unroll
      for (int r = 0; r < 4; r++) {
        if (row + r < M) {
          float val = acc[i][j][r] + bvv;
          if (mode == 0)
            ((float*)C)[(size_t)(row + r) * DIM + col] = val;
          else
            ((uint16_t*)C)[(size_t)(col >> 7) * ((size_t)SLEN * HD) +
                           (size_t)(row + r) * HD + (col & 127)] = f2b(val);
        }
      }
    }
  }
}

// --------------------------------------- RMSNorm + gamma + 3D RoPE for Q / K
// In/out (in-place): Qb/Kb head-split [12][SLEN][128] bf16. Params fp32.
__global__ __launch_bounds__(256) void norm_rope(
    uint16_t* __restrict__ Qb, uint16_t* __restrict__ Kb,
    const float* __restrict__ bq, const float* __restrict__ bk,
    const float* __restrict__ gq, const float* __restrict__ gk,
    const float* __restrict__ freqs, const int* __restrict__ gsz) {
  const int s = blockIdx.x;
  const int isK = blockIdx.y;
  uint32_t* B = (uint32_t*)(isK ? Kb : Qb);
  const float2* br = (const float2*)(isK ? bk : bq);
  const float2* gr = (const float2*)(isK ? gk : gq);
  const int tid = threadIdx.x;
  float va[3], vb[3];
  float ss = 0.f;
#pragma unroll
  for (int i = 0; i < 3; i++) {
    int p = tid + i * 256;  // pair index 0..767
    int h = p >> 6, j = p & 63;
    size_t a = (size_t)h * (SLEN * 64) + (size_t)s * 64 + j;
    uint32_t u = B[a];
    float2 ub = br[p];
    float x0 = b2f((uint16_t)(u & 0xffff)) + ub.x;
    float x1 = b2f((uint16_t)(u >> 16)) + ub.y;
    va[i] = x0; vb[i] = x1; ss += x0 * x0 + x1 * x1;
  }
#pragma unroll
  for (int o = 32; o > 0; o >>= 1) ss += __shfl_down(ss, o, 64);
  __shared__ float red[4];
  if ((tid & 63) == 0) red[tid >> 6] = ss;
  __syncthreads();
  ss = red[0] + red[1] + red[2] + red[3];
  const float rr = rsqrtf(ss * (1.0f / DIM) + 1e-6f);
  const int H = gsz[1], W = gsz[2];
  const int hw = H * W;
  const int fi = s / hw, rem = s - fi * hw;
  const int hi = rem / W, wi = rem - hi * W;
#pragma unroll
  for (int i = 0; i < 3; i++) {
    int p = tid + i * 256;
    int h = p >> 6, j = p & 63;
    int prow = (j < 22) ? fi : (j < 43) ? hi : wi;  // c0=22, c3=21
    float2 f2 = ((const float2*)freqs)[prow * 64 + j];
    float2 g2 = gr[p];
    float na = va[i] * rr * g2.x;
    float nb = vb[i] * rr * g2.y;
    float ra = na * f2.x - nb * f2.y;
    float rb = na * f2.y + nb * f2.x;
    size_t a = (size_t)h * (SLEN * 64) + (size_t)s * 64 + j;
    B[a] = (uint32_t)f2b(ra) | ((uint32_t)f2b(rb) << 16);
  }
}

// ----------------- V: bias(fp32) + reformat [12][SLEN][128] -> V^T [12][128][SPAD]
__global__ __launch_bounds__(256) void v_reformat(
    const uint16_t* __restrict__ Vb, const float* __restrict__ bv,
    uint16_t* __restrict__ VT) {
  __shared__ uint16_t t[128][136];
  const int head = blockIdx.x;
  const int s0 = blockIdx.y * 128;
  const int tid = threadIdx.x;
  const int cb = (tid & 15) * 8, rb = tid >> 4;
  const uint16_t* Vh = Vb + (size_t)head * SLEN * HD;
  float bvf[8];
#pragma unroll
  for (int q = 0; q < 8; q++) bvf[q] = bv[head * HD + cb + q];
#pragma unroll
  for (int pass = 0; pass < 8; pass++) {
    int r = rb + pass * 16;
    int s = s0 + r; int sc = s < SLEN ? s : SLEN - 1;
    uint16_t u[8];
    __builtin_memcpy(u, Vh + (size_t)sc * HD + cb, 16);
#pragma unroll
    for (int q = 0; q < 8; q++) t[r][cb + q] = f2b(b2f(u[q]) + bvf[q]);
  }
  __syncthreads();
  const int sb = (tid & 15) * 8, db = tid >> 4;
#pragma unroll
  for (int pass = 0; pass < 8; pass++) {
    int d = db + pass * 16;
    uint16_t out[8] __attribute__((aligned(16)));
#pragma unroll
    for (int i2 = 0; i2 < 8; i2++) {
      int s = s0 + sb + i2;
      out[i2] = (s < SLEN) ? t[sb + i2][d] : (uint16_t)0;
    }
    size_t base = ((size_t)head * HD + d) * SPAD + s0 + sb;
    if (s0 + sb + 8 <= SLEN) {
      __builtin_memcpy(VT + base, out, 16);
    } else {
#pragma unroll
      for (int i2 = 0; i2 < 8; i2++) {
        int s = s0 + sb + i2;
        if (s < SPAD) VT[base + i2] = out[i2];
      }
    }
  }
}

// ------------------------------------------------ flash attention (bf16 MFMA)
// grid (12 heads, 61 q-tiles of 64); 4 waves; wave owns 16 q rows, d=128.
// STATIC-MAX softmax: RMSNorm bounds |s| <= sqrt(128) < 12, so p=exp2(s*C1-C2)
// is exact softmax math (shift-invariant) with NO max reduction, NO rescale.
// Row-sum l accumulated per-lane, one 4-shfl reduction at the end.
__global__ __launch_bounds__(256) void attn(
    const uint16_t* __restrict__ Q, const uint16_t* __restrict__ K,
    const uint16_t* __restrict__ VT, uint16_t* __restrict__ O,
    const int* __restrict__ seq_lens) {
  __shared__ __align__(16) uint16_t sK[64 * SKP];   // [kk][d]  17.0 KB
  __shared__ __align__(16) uint16_t sV[128 * SVP];  // [d][kk]  17.4 KB
  __shared__ __align__(16) uint16_t sP[64 * SVP];   // [q][kk]   8.7 KB
  const int head = blockIdx.x;
  const int q0 = blockIdx.y * 64;
  const int tid = threadIdx.x;
  const int wave = tid >> 6, lane = tid & 63;
  int sl = seq_lens[0];
  const int seqlen = sl < SLEN ? sl : SLEN;
  const uint16_t* Qh = Q + (size_t)head * SLEN * HD;
  const uint16_t* Kh = K + (size_t)head * SLEN * HD;
  const uint16_t* Vh = VT + (size_t)head * HD * SPAD;

  const int fm = lane & 15;
  const int ko = (lane >> 4) * 8;

  // stage Q through sK once; pull this wave's fragments to registers
#pragma unroll
  for (int ps = 0; ps < 4; ps++) {
    int idx = tid + ps * 256;
    int row = idx >> 4, cc = (idx & 15) * 8;
    int qg = q0 + row; qg = qg < SLEN ? qg : SLEN - 1;
    st8(sK + row * SKP + cc, ld8bf(Qh + (size_t)qg * HD + cc));
  }
  __syncthreads();
  bf16x8 aq[4];
#pragma unroll
  for (int kc = 0; kc < 4; kc++)
    aq[kc] = ld8bf(sK + (wave * 16 + fm) * SKP + kc * 32 + ko);
  // loop-top barrier separates these reads from iter-0 K staging writes

  f32x4 o[8];
  const f32x4 z4 = {0.f, 0.f, 0.f, 0.f};
#pragma unroll
  for (int j = 0; j < 8; j++) o[j] = z4;
  float l_r[4] = {0.f, 0.f, 0.f, 0.f};  // per-lane partial row sums

  const float C1 = 0.08838834764831845f * 1.4426950408889634f;  // scale*log2e
  const float C2 = 12.0f * 1.4426950408889634f;                 // M*log2e

  for (int kv0 = 0; kv0 < SLEN; kv0 += 64) {
    __syncthreads();
    // stage K: 64 rows x 128 cols
#pragma unroll
    for (int ps = 0; ps < 4; ps++) {
      int idx = tid + ps * 256;
      int row = idx >> 4, cc = (idx & 15) * 8;
      int kg = kv0 + row; kg = kg < SLEN ? kg : SLEN - 1;
      st8(sK + row * SKP + cc, ld8bf(Kh + (size_t)kg * HD + cc));
    }
    // stage V^T: 128 rows(d) x 64 cols(kv)
#pragma unroll
    for (int ps = 0; ps < 4; ps++) {
      int idx = tid + ps * 256;
      int d = idx >> 3, cc = (idx & 7) * 8;
      st8(sV + d * SVP + cc, ld8bf(Vh + (size_t)d * SPAD + kv0 + cc));
    }
    __syncthreads();

    // QK^T : 16 mfma
    f32x4 sc[4];
#pragma unroll
    for (int kk = 0; kk < 4; kk++) sc[kk] = z4;
#pragma unroll
    for (int kc = 0; kc < 4; kc++) {
#pragma unroll
      for (int kk = 0; kk < 4; kk++) {
        bf16x8 bkf = ld8bf(sK + (kk * 16 + fm) * SKP + kc * 32 + ko);
        sc[kk] = __builtin_amdgcn_mfma_f32_16x16x32_bf16(aq[kc], bkf, sc[kk], 0, 0, 0);
      }
    }
    // static-max softmax: p = exp2(s*C1 - C2), masked -> 0; accumulate l
#pragma unroll
    for (int kk = 0; kk < 4; kk++) {
      int col = kv0 + kk * 16 + fm;
      bool valid = col < seqlen;
#pragma unroll
      for (int r = 0; r < 4; r++) {
        float p = valid ? exp2f(sc[kk][r] * C1 - C2) : 0.f;
        l_r[r] += p;
        sP[(wave * 16 + (lane >> 4) * 4 + r) * SVP + kk * 16 + fm] = f2b(p);
      }
    }
    __syncthreads();  // sP writes -> PV reads (kept: removal unproven safe)
    // PV : 16 mfma
#pragma unroll
    for (int kc = 0; kc < 2; kc++) {
      bf16x8 ap = ld8bf(sP + (wave * 16 + fm) * SVP + kc * 32 + ko);
#pragma unroll
      for (int j = 0; j < 8; j++) {
        bf16x8 bvf = ld8bf(sV + (j * 16 + fm) * SVP + kc * 32 + ko);
        o[j] = __builtin_amdgcn_mfma_f32_16x16x32_bf16(ap, bvf, o[j], 0, 0, 0);
      }
    }
  }
  // reduce l across the 16-lane row group (once, not per iter)
#pragma unroll
  for (int r = 0; r < 4; r++) {
#pragma unroll
    for (int off = 1; off < 16; off <<= 1) l_r[r] += __shfl_xor(l_r[r], off, 64);
  }
  // epilogue: normalize and write [s][head*128+d] (bf16 internal buffer)
#pragma unroll
  for (int r = 0; r < 4; r++) {
    int row = q0 + wave * 16 + (lane >> 4) * 4 + r;
    if (row < SLEN) {
      float inv = 1.0f / l_r[r];
#pragma unroll
      for (int j = 0; j < 8; j++) {
        int col = head * HD + j * 16 + fm;
        O[(size_t)row * DIM + col] = f2b(o[j][r] * inv);
      }
    }
  }
}

// ----------------------------------------------------------------- launcher
extern "C" void kernel_launch(void* const* d_in, const int* in_sizes, int n_in,
                              void* d_out, int out_size, void* d_ws, size_t ws_size,
                              hipStream_t stream) {
  const float* x      = (const float*)d_in[0];
  const int* seq_lens = (const int*)d_in[1];
  const int* gsz      = (const int*)d_in[2];
  const float* freqs  = (const float*)d_in[3];
  const float* Wq     = (const float*)d_in[4];
  const float* bq     = (const float*)d_in[5];
  const float* Wk     = (const float*)d_in[6];
  const float* bk     = (const float*)d_in[7];
  const float* Wv     = (const float*)d_in[8];
  const float* bv     = (const float*)d_in[9];
  const float* Wo     = (const float*)d_in[10];
  const float* bo     = (const float*)d_in[11];
  const float* gq     = (const float*)d_in[12];
  const float* gk     = (const float*)d_in[13];

  // workspace (~53 MB): xb aliases VTb (x consumed by gemms before v_reformat)
  char* p = (char*)d_ws;
  uint16_t* WT  = (uint16_t*)p; p += (size_t)DIM * DIM * 2;        //  4.72 MB
  uint16_t* Qb  = (uint16_t*)p; p += (size_t)NH * SLEN * HD * 2;   // 11.98 MB
  uint16_t* Kb  = (uint16_t*)p; p += (size_t)NH * SLEN * HD * 2;   // 11.98 MB
  uint16_t* Vb  = (uint16_t*)p; p += (size_t)NH * SLEN * HD * 2;   // 11.98 MB
  uint16_t* VTb = (uint16_t*)p; p += (size_t)NH * HD * SPAD * 2;   // 11.99 MB
  uint16_t* xb  = VTb;   // [SLEN][DIM] bf16 — dead before VTb written
  uint16_t* AO  = Vb;    // attn output overlays Vb (consumed by v_reformat)

  conv_x<<<dim3(2925), 256, 0, stream>>>(x, xb);

  transposeWf<<<dim3(48, 48), 256, 0, stream>>>(Wq, WT);
  gemm<<<dim3(31, 12), 256, 0, stream>>>(xb, WT, Qb, nullptr, SLEN, 1);
  transposeWf<<<dim3(48, 48), 256, 0, stream>>>(Wk, WT);
  gemm<<<dim3(31, 12), 256, 0, stream>>>(xb, WT, Kb, nullptr, SLEN, 1);
  transposeWf<<<dim3(48, 48), 256, 0, stream>>>(Wv, WT);
  gemm<<<dim3(31, 12), 256, 0, stream>>>(xb, WT, Vb, nullptr, SLEN, 1);

  norm_rope<<<dim3(SLEN, 2), 256, 0, stream>>>(Qb, Kb, bq, bk, gq, gk, freqs, gsz);
  v_reformat<<<dim3(NH, 31), 256, 0, stream>>>(Vb, bv, VTb);
  attn<<<dim3(NH, 61), 256, 0, stream>>>(Qb, Kb, VTb, AO, seq_lens);

  transposeWf<<<dim3(48, 48), 256, 0, stream>>>(Wo, WT);
  gemm<<<dim3(31, 12), 256, 0, stream>>>(AO, WT, d_out, bo, SLEN, 0);
}

// Round 10
// 543.386 us; speedup vs baseline: 1.7658x; 1.0932x over previous
//
#include <hip/hip_runtime.h>
#include <stdint.h>

// Inputs are FP32 (proven R4-R7 pass/fail matrix); output is FP32.
#define DIM 1536
#define SLEN 3900
#define SPAD 3904   // padded V^T row stride (16B-aligned rows)
#define NH 12
#define HD 128
#define SKP 136     // attn sK row stride (elems): 272B pitch breaks bank period
#define SVP 68      // attn sV/sP row stride (elems): 136B pitch

typedef __bf16 bf16x8 __attribute__((ext_vector_type(8)));
typedef float f32x4 __attribute__((ext_vector_type(4)));

__device__ __forceinline__ float b2f(uint16_t u) {
  union { uint32_t i; float f; } x; x.i = ((uint32_t)u) << 16; return x.f;
}
__device__ __forceinline__ uint16_t f2b(float f) {
  union { float f; uint32_t i; } x; x.f = f;
  uint32_t r = (x.i + 0x7fffu + ((x.i >> 16) & 1u)) >> 16;
  return (uint16_t)r;
}
__device__ __forceinline__ bf16x8 ld8bf(const uint16_t* p) {
  bf16x8 r; __builtin_memcpy(&r, p, 16); return r;
}
__device__ __forceinline__ void st8(uint16_t* p, bf16x8 v) {
  __builtin_memcpy(p, &v, 16);
}
// async global->LDS, 16B/lane; LDS dest = wave-uniform base + lane*16 (m97/m104)
__device__ __forceinline__ void gl_lds16(const void* g, void* l) {
  __builtin_amdgcn_global_load_lds((__attribute__((address_space(1))) void*)(g),
                                   (__attribute__((address_space(3))) void*)(l),
                                   16, 0, 0);
}

// ------------------------------------------------ x: fp32 -> bf16 (one pass)
__global__ __launch_bounds__(256) void conv_x(
    const float* __restrict__ x, uint16_t* __restrict__ xb) {
  int i = (blockIdx.x * 256 + threadIdx.x) * 8;  // n divisible by 8
  float a[8];
  __builtin_memcpy(a, x + i, 32);
  uint16_t t[8];
#pragma unroll
  for (int q = 0; q < 8; q++) t[q] = f2b(a[q]);
  __builtin_memcpy(xb + i, t, 16);
}

// --------------------- transpose all 4 W: fp32 in -> bf16^T out (z selects)
__global__ __launch_bounds__(256) void transposeW4(
    const float* __restrict__ w0, const float* __restrict__ w1,
    const float* __restrict__ w2, const float* __restrict__ w3,
    uint16_t* __restrict__ WT4) {
  __shared__ uint16_t t[32][33];
  const int z = blockIdx.z;
  const float* src = z == 0 ? w0 : z == 1 ? w1 : z == 2 ? w2 : w3;
  uint16_t* dst = WT4 + (size_t)z * DIM * DIM;
  const int bx = blockIdx.x * 32, by = blockIdx.y * 32;
  const int tx = threadIdx.x & 31, ty = threadIdx.x >> 5;  // ty 0..7
#pragma unroll
  for (int i = 0; i < 32; i += 8)
    t[ty + i][tx] = f2b(src[(size_t)(by + ty + i) * DIM + bx + tx]);
  __syncthreads();
#pragma unroll
  for (int i = 0; i < 32; i += 8)
    dst[(size_t)(bx + ty + i) * DIM + by + tx] = t[tx][ty + i];
}

// ------------------------------------------------- GEMM: C = A * BT^T (+bias)
// gl_lds staging (m97 idiom): unpadded 64B-pitch LDS (required: lane-ordered
// dest). mode 1: z selects BT slice + head-split bf16 out Cb + z*NH*SLEN*HD.
// mode 0: fp32 out Cf + bias. 128x128 tile, BK=32, 4 waves (2x2).
__global__ __launch_bounds__(256) void gemm(
    const uint16_t* __restrict__ A, const uint16_t* __restrict__ BT4,
    uint16_t* __restrict__ Cb, float* __restrict__ Cf,
    const float* __restrict__ bias, int M, int mode) {
  __shared__ __align__(16) uint16_t sA[128 * 32];
  __shared__ __align__(16) uint16_t sB[128 * 32];
  const int z = blockIdx.z;
  const uint16_t* BT = BT4 + (size_t)z * DIM * DIM;
  const int m0 = blockIdx.x * 128;
  const int n0 = blockIdx.y * 128;
  const int tid = threadIdx.x;
  const int wave = tid >> 6, lane = tid & 63;
  const int mh = (wave >> 1) * 64, nh = (wave & 1) * 64;
  const int lr = lane >> 2, lc = (lane & 3) * 8;  // staging row/col in 16-row slab
  const int r0 = wave * 32;                       // staging slab base row
  const int fm = mh + (lane & 15);
  const int fn = nh + (lane & 15);
  const int ko = (lane >> 4) * 8;

  f32x4 acc[4][4];
  const f32x4 z4 = {0.f, 0.f, 0.f, 0.f};
#pragma unroll
  for (int i = 0; i < 4; i++)
#pragma unroll
    for (int j = 0; j < 4; j++) acc[i][j] = z4;

  for (int k0 = 0; k0 < DIM; k0 += 32) {
    __syncthreads();  // protect previous iteration's LDS frag reads
#pragma unroll
    for (int j = 0; j < 2; j++) {
      int ra = m0 + r0 + j * 16 + lr; ra = ra < M ? ra : M - 1;
      gl_lds16(A + (size_t)ra * DIM + k0 + lc, (char*)sA + (r0 + j * 16) * 64);
      int rb = n0 + r0 + j * 16 + lr;
      gl_lds16(BT + (size_t)rb * DIM + k0 + lc, (char*)sB + (r0 + j * 16) * 64);
    }
    __builtin_amdgcn_s_waitcnt(0x0f70);  // vmcnt(0): drain gl_lds
    __syncthreads();
    bf16x8 fa[4], fb[4];
#pragma unroll
    for (int i = 0; i < 4; i++) {
      fa[i] = ld8bf(sA + (fm + i * 16) * 32 + ko);
      fb[i] = ld8bf(sB + (fn + i * 16) * 32 + ko);
    }
#pragma unroll
    for (int i = 0; i < 4; i++)
#pragma unroll
      for (int j = 0; j < 4; j++)
        acc[i][j] = __builtin_amdgcn_mfma_f32_16x16x32_bf16(fa[i], fb[j], acc[i][j], 0, 0, 0);
  }
  // epilogue: D row=(lane>>4)*4+r, col=lane&15 (verified m89/m91)
#pragma unroll
  for (int j = 0; j < 4; j++) {
    int col = n0 + nh + j * 16 + (lane & 15);
    float bvv = (mode == 0 && bias) ? bias[col] : 0.f;
#pragma unroll
    for (int i = 0; i < 4; i++) {
      int row = m0 + mh + i * 16 + (lane >> 4) * 4;
#pragma unroll
      for (int r = 0; r < 4; r++) {
        if (row + r < M) {
          float val = acc[i][j][r] + bvv;
          if (mode == 0)
            Cf[(size_t)(row + r) * DIM + col] = val;
          else
            Cb[(size_t)z * ((size_t)NH * SLEN * HD) +
               (size_t)(col >> 7) * ((size_t)SLEN * HD) +
               (size_t)(row + r) * HD + (col & 127)] = f2b(val);
        }
      }
    }
  }
}

// --------------------------------------- RMSNorm + gamma + 3D RoPE for Q / K
// In/out (in-place): Qb/Kb head-split [12][SLEN][128] bf16. Params fp32.
__global__ __launch_bounds__(256) void norm_rope(
    uint16_t* __restrict__ Qb, uint16_t* __restrict__ Kb,
    const float* __restrict__ bq, const float* __restrict__ bk,
    const float* __restrict__ gq, const float* __restrict__ gk,
    const float* __restrict__ freqs, const int* __restrict__ gsz) {
  const int s = blockIdx.x;
  const int isK = blockIdx.y;
  uint32_t* B = (uint32_t*)(isK ? Kb : Qb);
  const float2* br = (const float2*)(isK ? bk : bq);
  const float2* gr = (const float2*)(isK ? gk : gq);
  const int tid = threadIdx.x;
  float va[3], vb[3];
  float ss = 0.f;
#pragma unroll
  for (int i = 0; i < 3; i++) {
    int p = tid + i * 256;  // pair index 0..767
    int h = p >> 6, j = p & 63;
    size_t a = (size_t)h * (SLEN * 64) + (size_t)s * 64 + j;
    uint32_t u = B[a];
    float2 ub = br[p];
    float x0 = b2f((uint16_t)(u & 0xffff)) + ub.x;
    float x1 = b2f((uint16_t)(u >> 16)) + ub.y;
    va[i] = x0; vb[i] = x1; ss += x0 * x0 + x1 * x1;
  }
#pragma unroll
  for (int o = 32; o > 0; o >>= 1) ss += __shfl_down(ss, o, 64);
  __shared__ float red[4];
  if ((tid & 63) == 0) red[tid >> 6] = ss;
  __syncthreads();
  ss = red[0] + red[1] + red[2] + red[3];
  const float rr = rsqrtf(ss * (1.0f / DIM) + 1e-6f);
  const int H = gsz[1], W = gsz[2];
  const int hw = H * W;
  const int fi = s / hw, rem = s - fi * hw;
  const int hi = rem / W, wi = rem - hi * W;
#pragma unroll
  for (int i = 0; i < 3; i++) {
    int p = tid + i * 256;
    int h = p >> 6, j = p & 63;
    int prow = (j < 22) ? fi : (j < 43) ? hi : wi;  // c0=22, c3=21
    float2 f2 = ((const float2*)freqs)[prow * 64 + j];
    float2 g2 = gr[p];
    float na = va[i] * rr * g2.x;
    float nb = vb[i] * rr * g2.y;
    float ra = na * f2.x - nb * f2.y;
    float rb = na * f2.y + nb * f2.x;
    size_t a = (size_t)h * (SLEN * 64) + (size_t)s * 64 + j;
    B[a] = (uint32_t)f2b(ra) | ((uint32_t)f2b(rb) << 16);
  }
}

// ----------------- V: bias(fp32) + reformat [12][SLEN][128] -> V^T [12][128][SPAD]
__global__ __launch_bounds__(256) void v_reformat(
    const uint16_t* __restrict__ Vb, const float* __restrict__ bv,
    uint16_t* __restrict__ VT) {
  __shared__ uint16_t t[128][136];
  const int head = blockIdx.x;
  const int s0 = blockIdx.y * 128;
  const int tid = threadIdx.x;
  const int cb = (tid & 15) * 8, rb = tid >> 4;
  const uint16_t* Vh = Vb + (size_t)head * SLEN * HD;
  float bvf[8];
#pragma unroll
  for (int q = 0; q < 8; q++) bvf[q] = bv[head * HD + cb + q];
#pragma unroll
  for (int pass = 0; pass < 8; pass++) {
    int r = rb + pass * 16;
    int s = s0 + r; int sc = s < SLEN ? s : SLEN - 1;
    uint16_t u[8];
    __builtin_memcpy(u, Vh + (size_t)sc * HD + cb, 16);
#pragma unroll
    for (int q = 0; q < 8; q++) t[r][cb + q] = f2b(b2f(u[q]) + bvf[q]);
  }
  __syncthreads();
  const int sb = (tid & 15) * 8, db = tid >> 4;
#pragma unroll
  for (int pass = 0; pass < 8; pass++) {
    int d = db + pass * 16;
    uint16_t out[8] __attribute__((aligned(16)));
#pragma unroll
    for (int i2 = 0; i2 < 8; i2++) {
      int s = s0 + sb + i2;
      out[i2] = (s < SLEN) ? t[sb + i2][d] : (uint16_t)0;
    }
    size_t base = ((size_t)head * HD + d) * SPAD + s0 + sb;
    if (s0 + sb + 8 <= SLEN) {
      __builtin_memcpy(VT + base, out, 16);
    } else {
#pragma unroll
      for (int i2 = 0; i2 < 8; i2++) {
        int s = s0 + sb + i2;
        if (s < SPAD) VT[base + i2] = out[i2];
      }
    }
  }
}

// ------------------------------------------------ flash attention (bf16 MFMA)
// grid (12 heads, 61 q-tiles of 64); 4 waves; wave owns 16 q rows, d=128.
// Static-max softmax (RMSNorm bounds |s|<=sqrt(128)<12). UNCHANGED from R9.
__global__ __launch_bounds__(256) void attn(
    const uint16_t* __restrict__ Q, const uint16_t* __restrict__ K,
    const uint16_t* __restrict__ VT, uint16_t* __restrict__ O,
    const int* __restrict__ seq_lens) {
  __shared__ __align__(16) uint16_t sK[64 * SKP];   // [kk][d]  17.0 KB
  __shared__ __align__(16) uint16_t sV[128 * SVP];  // [d][kk]  17.4 KB
  __shared__ __align__(16) uint16_t sP[64 * SVP];   // [q][kk]   8.7 KB
  const int head = blockIdx.x;
  const int q0 = blockIdx.y * 64;
  const int tid = threadIdx.x;
  const int wave = tid >> 6, lane = tid & 63;
  int sl = seq_lens[0];
  const int seqlen = sl < SLEN ? sl : SLEN;
  const uint16_t* Qh = Q + (size_t)head * SLEN * HD;
  const uint16_t* Kh = K + (size_t)head * SLEN * HD;
  const uint16_t* Vh = VT + (size_t)head * HD * SPAD;

  const int fm = lane & 15;
  const int ko = (lane >> 4) * 8;

  // stage Q through sK once; pull this wave's fragments to registers
#pragma unroll
  for (int ps = 0; ps < 4; ps++) {
    int idx = tid + ps * 256;
    int row = idx >> 4, cc = (idx & 15) * 8;
    int qg = q0 + row; qg = qg < SLEN ? qg : SLEN - 1;
    st8(sK + row * SKP + cc, ld8bf(Qh + (size_t)qg * HD + cc));
  }
  __syncthreads();
  bf16x8 aq[4];
#pragma unroll
  for (int kc = 0; kc < 4; kc++)
    aq[kc] = ld8bf(sK + (wave * 16 + fm) * SKP + kc * 32 + ko);

  f32x4 o[8];
  const f32x4 z4 = {0.f, 0.f, 0.f, 0.f};
#pragma unroll
  for (int j = 0; j < 8; j++) o[j] = z4;
  float l_r[4] = {0.f, 0.f, 0.f, 0.f};  // per-lane partial row sums

  const float C1 = 0.08838834764831845f * 1.4426950408889634f;  // scale*log2e
  const float C2 = 12.0f * 1.4426950408889634f;                 // M*log2e

  for (int kv0 = 0; kv0 < SLEN; kv0 += 64) {
    __syncthreads();
#pragma unroll
    for (int ps = 0; ps < 4; ps++) {
      int idx = tid + ps * 256;
      int row = idx >> 4, cc = (idx & 15) * 8;
      int kg = kv0 + row; kg = kg < SLEN ? kg : SLEN - 1;
      st8(sK + row * SKP + cc, ld8bf(Kh + (size_t)kg * HD + cc));
    }
#pragma unroll
    for (int ps = 0; ps < 4; ps++) {
      int idx = tid + ps * 256;
      int d = idx >> 3, cc = (idx & 7) * 8;
      st8(sV + d * SVP + cc, ld8bf(Vh + (size_t)d * SPAD + kv0 + cc));
    }
    __syncthreads();

    // QK^T : 16 mfma
    f32x4 sc[4];
#pragma unroll
    for (int kk = 0; kk < 4; kk++) sc[kk] = z4;
#pragma unroll
    for (int kc = 0; kc < 4; kc++) {
#pragma unroll
      for (int kk = 0; kk < 4; kk++) {
        bf16x8 bkf = ld8bf(sK + (kk * 16 + fm) * SKP + kc * 32 + ko);
        sc[kk] = __builtin_amdgcn_mfma_f32_16x16x32_bf16(aq[kc], bkf, sc[kk], 0, 0, 0);
      }
    }
    // static-max softmax: p = exp2(s*C1 - C2), masked -> 0; accumulate l
#pragma unroll
    for (int kk = 0; kk < 4; kk++) {
      int col = kv0 + kk * 16 + fm;
      bool valid = col < seqlen;
#pragma unroll
      for (int r = 0; r < 4; r++) {
        float p = valid ? exp2f(sc[kk][r] * C1 - C2) : 0.f;
        l_r[r] += p;
        sP[(wave * 16 + (lane >> 4) * 4 + r) * SVP + kk * 16 + fm] = f2b(p);
      }
    }
    __syncthreads();
    // PV : 16 mfma
#pragma unroll
    for (int kc = 0; kc < 2; kc++) {
      bf16x8 ap = ld8bf(sP + (wave * 16 + fm) * SVP + kc * 32 + ko);
#pragma unroll
      for (int j = 0; j < 8; j++) {
        bf16x8 bvf = ld8bf(sV + (j * 16 + fm) * SVP + kc * 32 + ko);
        o[j] = __builtin_amdgcn_mfma_f32_16x16x32_bf16(ap, bvf, o[j], 0, 0, 0);
      }
    }
  }
  // reduce l across the 16-lane row group (once)
#pragma unroll
  for (int r = 0; r < 4; r++) {
#pragma unroll
    for (int off = 1; off < 16; off <<= 1) l_r[r] += __shfl_xor(l_r[r], off, 64);
  }
  // epilogue
#pragma unroll
  for (int r = 0; r < 4; r++) {
    int row = q0 + wave * 16 + (lane >> 4) * 4 + r;
    if (row < SLEN) {
      float inv = 1.0f / l_r[r];
#pragma unroll
      for (int j = 0; j < 8; j++) {
        int col = head * HD + j * 16 + fm;
        O[(size_t)row * DIM + col] = f2b(o[j][r] * inv);
      }
    }
  }
}

// ----------------------------------------------------------------- launcher
extern "C" void kernel_launch(void* const* d_in, const int* in_sizes, int n_in,
                              void* d_out, int out_size, void* d_ws, size_t ws_size,
                              hipStream_t stream) {
  const float* x      = (const float*)d_in[0];
  const int* seq_lens = (const int*)d_in[1];
  const int* gsz      = (const int*)d_in[2];
  const float* freqs  = (const float*)d_in[3];
  const float* Wq     = (const float*)d_in[4];
  const float* bq     = (const float*)d_in[5];
  const float* Wk     = (const float*)d_in[6];
  const float* bk     = (const float*)d_in[7];
  const float* Wv     = (const float*)d_in[8];
  const float* bv     = (const float*)d_in[9];
  const float* Wo     = (const float*)d_in[10];
  const float* bo     = (const float*)d_in[11];
  const float* gq     = (const float*)d_in[12];
  const float* gk     = (const float*)d_in[13];

  // workspace (~66.8 MB)
  char* p = (char*)d_ws;
  uint16_t* WT4 = (uint16_t*)p; p += (size_t)4 * DIM * DIM * 2;    // 18.87 MB
  uint16_t* Qb  = (uint16_t*)p; p += (size_t)NH * SLEN * HD * 2;   // 11.98 MB
  uint16_t* Kb  = (uint16_t*)p; p += (size_t)NH * SLEN * HD * 2;   // 11.98 MB
  uint16_t* Vb  = (uint16_t*)p; p += (size_t)NH * SLEN * HD * 2;   // 11.98 MB
  uint16_t* VTb = (uint16_t*)p; p += (size_t)NH * HD * SPAD * 2;   // 11.99 MB
  uint16_t* xb  = VTb;   // [SLEN][DIM] bf16 — dead before VTb written
  uint16_t* AO  = Vb;    // attn output overlays Vb (consumed by v_reformat)

  conv_x<<<dim3(2925), 256, 0, stream>>>(x, xb);
  transposeW4<<<dim3(48, 48, 4), 256, 0, stream>>>(Wq, Wk, Wv, Wo, WT4);

  // QKV batched: z selects weight slice + output third (Qb,Kb,Vb contiguous)
  gemm<<<dim3(31, 12, 3), 256, 0, stream>>>(xb, WT4, Qb, nullptr, nullptr, SLEN, 1);

  norm_rope<<<dim3(SLEN, 2), 256, 0, stream>>>(Qb, Kb, bq, bk, gq, gk, freqs, gsz);
  v_reformat<<<dim3(NH, 31), 256, 0, stream>>>(Vb, bv, VTb);
  attn<<<dim3(NH, 61), 256, 0, stream>>>(Qb, Kb, VTb, AO, seq_lens);

  gemm<<<dim3(31, 12, 1), 256, 0, stream>>>(AO, WT4 + (size_t)3 * DIM * DIM,
                                            nullptr, (float*)d_out, bo, SLEN, 0);
}